// Round 1
// baseline (590.525 us; speedup 1.0000x reference)
//
#include <hip/hip_runtime.h>
#include <math.h>

#define BATCH 4
#define NSUP 25
#define NQ   75
#define CH   640
#define HW   100
#define NWAY 5
#define KSHOT 5
#define NSYS (BATCH*NQ)   // 300
#define MS   (NWAY*HW)    // 500
#define MQ   HW           // 100

// ---------------- K1: class mean of support ----------------
__global__ void k_supmean(const float* __restrict__ sup, float* __restrict__ supmean) {
    int idx = blockIdx.x * 256 + threadIdx.x;
    if (idx >= BATCH*NWAY*CH*HW) return;
    int m = idx % HW;
    int c = (idx / HW) % CH;
    int n = (idx / (HW*CH)) % NWAY;
    int b = idx / (HW*CH*NWAY);
    const float* base = sup + (((size_t)(b*NSUP + n*KSHOT)*CH + c)*HW + m);
    float acc = 0.f;
#pragma unroll
    for (int k = 0; k < KSHOT; ++k) acc += base[(size_t)k*CH*HW];
    supmean[idx] = acc * 0.2f;
}

// ---------------- K2/K3: inverse column norms over channel axis ----------------
// input viewed as panels of [CH][HW]; one block per panel, threads t<HW own column t
__global__ void k_invnorm(const float* __restrict__ in, float* __restrict__ inv) {
    int p = blockIdx.x;
    int t = threadIdx.x;
    if (t >= HW) return;
    const float* base = in + (size_t)p*CH*HW + t;
    float acc = 0.f;
    for (int c = 0; c < CH; ++c) { float v = base[(size_t)c*HW]; acc += v*v; }
    inv[p*HW + t] = 1.0f / (1e-16f + sqrtf(acc));
}

// ---------------- K4: S = (qry_n)^T (sup_n), fp32 tiled GEMM ----------------
// per batch: M=7500 (q*100+m), N=500 (n*100+s), K=640 (c)
#define BM 64
#define BN 64
#define BK 32
__global__ __launch_bounds__(256) void k_gemm_s(
        const float* __restrict__ qry, const float* __restrict__ supmean,
        const float* __restrict__ invq, const float* __restrict__ invs,
        float* __restrict__ S) {
    __shared__ __align__(16) float As[BK][BM];
    __shared__ __align__(16) float Bs[BK][BN];
    int b  = blockIdx.z;
    int rt = blockIdx.y;   // 0..117
    int ct = blockIdx.x;   // 0..7
    int t  = threadIdx.x;
    int tx = t % 16, ty = t / 16;
    int row0 = rt * BM;
    int col0 = ct * BN;
    float acc[4][4] = {};
    const float* qb = qry     + (size_t)b*NQ*CH*HW;
    const float* sb = supmean + (size_t)b*NWAY*CH*HW;

    for (int k0 = 0; k0 < CH; k0 += BK) {
#pragma unroll
        for (int i = 0; i < 8; ++i) {              // A tile: 64 rows x 32 k
            int l = t + i*256;
            int rloc = l % BM;
            int kloc = l / BM;
            int r = row0 + rloc;
            float v = 0.f;
            if (r < NQ*HW) {
                int q = r / HW, m = r % HW;
                v = qb[((size_t)q*CH + (k0+kloc))*HW + m];
            }
            As[kloc][rloc] = v;
        }
#pragma unroll
        for (int i = 0; i < 8; ++i) {              // B tile: 64 cols x 32 k
            int l = t + i*256;
            int cloc = l % BN;
            int kloc = l / BN;
            int cc = col0 + cloc;
            float v = 0.f;
            if (cc < MS) {
                int n = cc / HW, s = cc % HW;
                v = sb[((size_t)n*CH + (k0+kloc))*HW + s];
            }
            Bs[kloc][cloc] = v;
        }
        __syncthreads();
#pragma unroll
        for (int k = 0; k < BK; ++k) {
            float4 av = *reinterpret_cast<const float4*>(&As[k][ty*4]);
            float4 bv = *reinterpret_cast<const float4*>(&Bs[k][tx*4]);
            acc[0][0] += av.x*bv.x; acc[0][1] += av.x*bv.y; acc[0][2] += av.x*bv.z; acc[0][3] += av.x*bv.w;
            acc[1][0] += av.y*bv.x; acc[1][1] += av.y*bv.y; acc[1][2] += av.y*bv.z; acc[1][3] += av.y*bv.w;
            acc[2][0] += av.z*bv.x; acc[2][1] += av.z*bv.y; acc[2][2] += av.z*bv.z; acc[2][3] += av.z*bv.w;
            acc[3][0] += av.w*bv.x; acc[3][1] += av.w*bv.y; acc[3][2] += av.w*bv.z; acc[3][3] += av.w*bv.w;
        }
        __syncthreads();
    }
#pragma unroll
    for (int ii = 0; ii < 4; ++ii) {
        int r = row0 + ty*4 + ii;
        if (r >= NQ*HW) continue;
        float qi = invq[b*NQ*HW + r];
#pragma unroll
        for (int jj = 0; jj < 4; ++jj) {
            int cc = col0 + tx*4 + jj;
            if (cc < MS)
                S[((size_t)b*NQ*HW + r)*MS + cc] = acc[ii][jj] * qi * invs[b*MS + cc];
        }
    }
}

// ---------------- K5a: row stats (gamma=20 softmax over 500 cols) ----------------
__global__ void k_rowstats(const float* __restrict__ S,
                           float* __restrict__ m20, float* __restrict__ rd20) {
    int row = blockIdx.x;           // 0..29999  (sys*100 + j)
    int t = threadIdx.x;            // 64
    const float* r = S + (size_t)row*MS;
    float mx = -1e30f;
    for (int c = t; c < MS; c += 64) mx = fmaxf(mx, r[c]);
    for (int off = 32; off; off >>= 1) mx = fmaxf(mx, __shfl_xor(mx, off));
    float s = 0.f;
    for (int c = t; c < MS; c += 64) s += __expf(20.f*(r[c]-mx));
    for (int off = 32; off; off >>= 1) s += __shfl_xor(s, off);
    if (t == 0) { m20[row] = mx; rd20[row] = 1.0f/s; }
}

// ---------------- K5b: col stats (gamma2=10 softmax over 100 rows) ----------------
__global__ void k_colstats(const float* __restrict__ S,
                           float* __restrict__ m10, float* __restrict__ rd10) {
    int sys = blockIdx.x;           // 0..299
    int t = threadIdx.x;            // 512, cols t<500
    if (t >= MS) return;
    const float* base = S + (size_t)sys*MQ*MS + t;
    float mx = -1e30f;
    for (int i = 0; i < MQ; ++i) mx = fmaxf(mx, base[(size_t)i*MS]);
    float s = 0.f;
    for (int i = 0; i < MQ; ++i) s += __expf(10.f*(base[(size_t)i*MS]-mx));
    m10[sys*MS + t] = mx;
    rd10[sys*MS + t] = 1.0f/s;
}

// ---------------- K6: B[i][j] = sum_col P[i][col]*Q[j][col], rhs ----------------
// P = T_qs (col-softmax, gamma 10), Q = T_sq (row-softmax, gamma 20)
#define KC 50
__global__ __launch_bounds__(256) void k_formB(
        const float* __restrict__ S,
        const float* __restrict__ m10, const float* __restrict__ rd10,
        const float* __restrict__ m20, const float* __restrict__ rd20,
        float* __restrict__ Bmat, float* __restrict__ rhs) {
    __shared__ float P[MQ][KC+1];
    __shared__ float Q[MQ][KC+1];
    int sys = blockIdx.x;
    int t = threadIdx.x;
    int tx = t % 25, ty = t / 25;    // ty 0..10 (ty<10 active for compute)
    float acc[10][4] = {};
    float rs = 0.f;
    const float* Sb   = S    + (size_t)sys*MQ*MS;
    const float* m10b = m10  + sys*MS;
    const float* r10b = rd10 + sys*MS;
    const float* m20b = m20  + sys*MQ;
    const float* r20b = rd20 + sys*MQ;

    for (int col0 = 0; col0 < MS; col0 += KC) {
        __syncthreads();
        for (int l = t; l < MQ*KC; l += 256) {
            int r = l / KC, cc = l % KC;
            float v = Sb[(size_t)r*MS + col0 + cc];
            P[r][cc] = __expf(10.f*(v - m10b[col0+cc])) * r10b[col0+cc];
            Q[r][cc] = __expf(20.f*(v - m20b[r])) * r20b[r];
        }
        __syncthreads();
        if (t < MQ) {
#pragma unroll
            for (int cc = 0; cc < KC; ++cc) rs += P[t][cc];
        }
        if (ty < 10) {
            for (int cc = 0; cc < KC; ++cc) {
                float q0 = Q[tx*4+0][cc], q1 = Q[tx*4+1][cc];
                float q2 = Q[tx*4+2][cc], q3 = Q[tx*4+3][cc];
#pragma unroll
                for (int ii = 0; ii < 10; ++ii) {
                    float pv = P[ty*10+ii][cc];
                    acc[ii][0] += pv*q0; acc[ii][1] += pv*q1;
                    acc[ii][2] += pv*q2; acc[ii][3] += pv*q3;
                }
            }
        }
    }
    if (ty < 10) {
        for (int ii = 0; ii < 10; ++ii)
            for (int jj = 0; jj < 4; ++jj)
                Bmat[(size_t)sys*MQ*MQ + (size_t)(ty*10+ii)*MQ + tx*4+jj] = acc[ii][jj];
    }
    if (t < MQ) rhs[sys*MQ + t] = 1.0f + 0.5f*rs;
}

// ---------------- K7: Jacobi solve (I - 0.25 B) x = rhs, normalize ----------------
__global__ __launch_bounds__(128) void k_solve(
        const float* __restrict__ Bmat, const float* __restrict__ rhs,
        float* __restrict__ out) {
    __shared__ float Bsh[MQ][MQ+1];
    __shared__ float xs[MQ];
    __shared__ float rh[MQ];
    __shared__ float partial[2];
    int sys = blockIdx.x;
    int t = threadIdx.x;
    const float* Bg = Bmat + (size_t)sys*MQ*MQ;
    for (int l = t; l < MQ*MQ; l += 128) Bsh[l/MQ][l%MQ] = Bg[l];
    if (t < MQ) { rh[t] = rhs[sys*MQ+t]; xs[t] = rh[t]; }
    __syncthreads();
    for (int it = 0; it < 30; ++it) {
        float s = 0.f;
        if (t < MQ) {
            for (int j = 0; j < MQ; ++j) s += Bsh[t][j]*xs[j];
        }
        __syncthreads();
        if (t < MQ) xs[t] = rh[t] + 0.25f*s;
        __syncthreads();
    }
    float kv = (t < MQ) ? (xs[t] - 1.0f) : 0.f;
    float s = kv;
    for (int off = 32; off; off >>= 1) s += __shfl_xor(s, off);
    if ((t & 63) == 0) partial[t >> 6] = s;
    __syncthreads();
    float tot = partial[0] + partial[1];
    if (t < MQ) out[sys*MQ + t] = kv / tot;
}

extern "C" void kernel_launch(void* const* d_in, const int* in_sizes, int n_in,
                              void* d_out, int out_size, void* d_ws, size_t ws_size,
                              hipStream_t stream) {
    const float* sup = (const float*)d_in[0];
    const float* qry = (const float*)d_in[1];
    float* out = (float*)d_out;
    float* ws  = (float*)d_ws;

    float* supmean = ws;                       // 1,280,000
    float* invs    = supmean + 1280000;        // 2,000
    float* invq    = invs + 2000;              // 30,000
    float* Smat    = invq + 30000;             // 15,000,000
    float* m20     = Smat + 15000000;          // 30,000
    float* rd20    = m20 + 30000;              // 30,000
    float* m10     = rd20 + 30000;             // 150,000
    float* rd10    = m10 + 150000;             // 150,000
    float* Bm      = rd10 + 150000;            // 3,000,000
    float* rh      = Bm + 3000000;             // 30,000

    k_supmean<<<(BATCH*NWAY*CH*HW + 255)/256, 256, 0, stream>>>(sup, supmean);
    k_invnorm<<<BATCH*NWAY, 128, 0, stream>>>(supmean, invs);
    k_invnorm<<<BATCH*NQ, 128, 0, stream>>>(qry, invq);
    k_gemm_s<<<dim3(8, 118, BATCH), 256, 0, stream>>>(qry, supmean, invq, invs, Smat);
    k_rowstats<<<NSYS*MQ, 64, 0, stream>>>(Smat, m20, rd20);
    k_colstats<<<NSYS, 512, 0, stream>>>(Smat, m10, rd10);
    k_formB<<<NSYS, 256, 0, stream>>>(Smat, m10, rd10, m20, rd20, Bm, rh);
    k_solve<<<NSYS, 128, 0, stream>>>(Bm, rh, out);
}

// Round 2
// 489.429 us; speedup vs baseline: 1.2066x; 1.2066x over previous
//
#include <hip/hip_runtime.h>
#include <math.h>

#define BATCH 4
#define NSUP 25
#define NQ   75
#define CH   640
#define HW   100
#define NWAY 5
#define KSHOT 5
#define NSYS (BATCH*NQ)   // 300
#define MS   (NWAY*HW)    // 500
#define MQ   HW           // 100
#define MTOT (NQ*HW)      // 7500 rows per batch

typedef __attribute__((ext_vector_type(8))) short bf16x8;
typedef __attribute__((ext_vector_type(4))) float f32x4;

__device__ __forceinline__ ushort f2bf(float f) {
    unsigned u = __float_as_uint(f);
    u += 0x7fff + ((u >> 16) & 1);          // RNE
    return (ushort)(u >> 16);
}
__device__ __forceinline__ float bf2f(ushort h) {
    return __uint_as_float(((unsigned)h) << 16);
}

#define GLD_LDS16(gp, lp) __builtin_amdgcn_global_load_lds( \
    (const __attribute__((address_space(1))) unsigned*)(const void*)(gp), \
    (__attribute__((address_space(3))) unsigned*)(void*)(lp), 16, 0, 0)

// ---------------- K1: class mean of support ----------------
__global__ void k_supmean(const float* __restrict__ sup, float* __restrict__ supmean) {
    int idx = blockIdx.x * 256 + threadIdx.x;
    if (idx >= BATCH*NWAY*CH*HW) return;
    int m = idx % HW;
    int c = (idx / HW) % CH;
    int n = (idx / (HW*CH)) % NWAY;
    int b = idx / (HW*CH*NWAY);
    const float* base = sup + (((size_t)(b*NSUP + n*KSHOT)*CH + c)*HW + m);
    float acc = 0.f;
#pragma unroll
    for (int k = 0; k < KSHOT; ++k) acc += base[(size_t)k*CH*HW];
    supmean[idx] = acc * 0.2f;
}

// ---------------- K2: inverse column norms over channel axis ----------------
__global__ void k_invnorm(const float* __restrict__ in, float* __restrict__ inv) {
    int p = blockIdx.x;
    int t = threadIdx.x;
    if (t >= HW) return;
    const float* base = in + (size_t)p*CH*HW + t;
    float acc = 0.f;
    for (int c = 0; c < CH; ++c) { float v = base[(size_t)c*HW]; acc += v*v; }
    inv[p*HW + t] = 1.0f / (1e-16f + sqrtf(acc));
}

// ---------------- K3: transpose + normalize + bf16 hi/lo split ----------------
// in: [planes][CH][HW] fp32  ->  hi/lo: [plane*HW + m][CH] bf16
__global__ __launch_bounds__(256) void k_prep(const float* __restrict__ in,
        const float* __restrict__ inv, ushort* __restrict__ hi, ushort* __restrict__ lo) {
    __shared__ float tile[64][65];
    int p  = blockIdx.z;
    int c0 = blockIdx.x * 64;
    int m0 = blockIdx.y * 64;
    int t  = threadIdx.x;
    const float* ib = in + (size_t)p*CH*HW;
#pragma unroll
    for (int i = 0; i < 16; ++i) {
        int l = i*256 + t;
        int cl = l >> 6, ml = l & 63;
        int m = m0 + ml;
        tile[cl][ml] = (m < HW) ? ib[(size_t)(c0+cl)*HW + m] : 0.f;
    }
    __syncthreads();
#pragma unroll
    for (int i = 0; i < 16; ++i) {
        int l = i*256 + t;
        int ml = l >> 6, cl = l & 63;
        int m = m0 + ml;
        if (m < HW) {
            size_t r = (size_t)p*HW + m;
            float v = tile[cl][ml] * inv[r];
            ushort h = f2bf(v);
            float fl = v - bf2f(h);
            hi[r*CH + c0 + cl] = h;
            lo[r*CH + c0 + cl] = f2bf(fl);
        }
    }
}

// ---------------- K4: split-bf16 MFMA GEMM  S = A * B^T ----------------
// A: [b*7500 + r][640] bf16 (hi/lo), B: [b*500 + cc][640] bf16 (hi/lo)
// tile 128x64, BK=64, 4 waves in 2x2, 16x16x32 MFMA, 3-product split
#define BM 128
#define BN 64
#define BK 64
#define NKT (CH/BK)
__global__ __launch_bounds__(256) void k_gemm(
        const ushort* __restrict__ Ah, const ushort* __restrict__ Al,
        const ushort* __restrict__ Bh, const ushort* __restrict__ Bl,
        float* __restrict__ S) {
    __shared__ __align__(1024) char lds[49152];
    // layout: AH [0,16K)  AL [16K,32K)  BH [32K,40K)  BL [40K,48K)
    int b  = blockIdx.z;
    int rt = blockIdx.y;
    int ct = blockIdx.x;
    int t  = threadIdx.x;
    int lane = t & 63, w = t >> 6;
    int row0 = rt * BM, col0 = ct * BN;

    // staging source offsets (pre-swizzled so linear LDS dest + swizzled read match)
    size_t aoff[4]; size_t boff[2];
    int lbase[4];
#pragma unroll
    for (int i = 0; i < 4; ++i) {
        int X = i*4096 + t*16;
        int L = X ^ (((X >> 7) & 7) << 4);   // involution within a 128B row
        int row = L >> 7;
        int kb  = L & 127;                   // byte within row (bf16*2)
        int gr = row0 + row; if (gr > MTOT-1) gr = MTOT-1;
        aoff[i] = ((size_t)b*MTOT + gr)*CH + (kb >> 1);
        lbase[i] = i*4096 + (w << 10);       // wave-uniform LDS base
    }
#pragma unroll
    for (int i = 0; i < 2; ++i) {
        int X = i*4096 + t*16;
        int L = X ^ (((X >> 7) & 7) << 4);
        int col = L >> 7;
        int kb  = L & 127;
        int gc = col0 + col; if (gc > MS-1) gc = MS-1;
        boff[i] = ((size_t)b*MS + gc)*CH + (kb >> 1);
    }

    f32x4 acc[4][2];
#pragma unroll
    for (int mi = 0; mi < 4; ++mi)
#pragma unroll
        for (int ni = 0; ni < 2; ++ni) acc[mi][ni] = (f32x4){0.f,0.f,0.f,0.f};

    int wr = w >> 1, wc = w & 1;
    const char* AHl = lds;
    const char* ALl = lds + 16384;
    const char* BHl = lds + 32768;
    const char* BLl = lds + 40960;

    for (int kt = 0; kt < NKT; ++kt) {
        size_t ka = (size_t)kt * BK;
#pragma unroll
        for (int i = 0; i < 4; ++i) {
            GLD_LDS16(Ah + aoff[i] + ka, lds + lbase[i]);
            GLD_LDS16(Al + aoff[i] + ka, lds + 16384 + lbase[i]);
        }
#pragma unroll
        for (int i = 0; i < 2; ++i) {
            GLD_LDS16(Bh + boff[i] + ka, lds + 32768 + lbase[i]);
            GLD_LDS16(Bl + boff[i] + ka, lds + 40960 + lbase[i]);
        }
        __syncthreads();
        int kg = lane >> 4;
#pragma unroll
        for (int ks = 0; ks < 2; ++ks) {
            bf16x8 bh[2], bl[2];
#pragma unroll
            for (int ni = 0; ni < 2; ++ni) {
                int colr = wc*32 + ni*16 + (lane & 15);
                int L = colr*128 + ks*64 + kg*16;
                int P = L ^ ((colr & 7) << 4);
                bh[ni] = *(const bf16x8*)(BHl + P);
                bl[ni] = *(const bf16x8*)(BLl + P);
            }
#pragma unroll
            for (int mi = 0; mi < 4; ++mi) {
                int rowr = wr*64 + mi*16 + (lane & 15);
                int L = rowr*128 + ks*64 + kg*16;
                int P = L ^ ((rowr & 7) << 4);
                bf16x8 ah = *(const bf16x8*)(AHl + P);
                bf16x8 al = *(const bf16x8*)(ALl + P);
#pragma unroll
                for (int ni = 0; ni < 2; ++ni) {
                    acc[mi][ni] = __builtin_amdgcn_mfma_f32_16x16x32_bf16(ah, bh[ni], acc[mi][ni], 0, 0, 0);
                    acc[mi][ni] = __builtin_amdgcn_mfma_f32_16x16x32_bf16(ah, bl[ni], acc[mi][ni], 0, 0, 0);
                    acc[mi][ni] = __builtin_amdgcn_mfma_f32_16x16x32_bf16(al, bh[ni], acc[mi][ni], 0, 0, 0);
                }
            }
        }
        __syncthreads();
    }
    // epilogue: C layout col=lane&15, row=(lane>>4)*4+reg
    int colb = col0 + wc*32 + (lane & 15);
    int rowb = row0 + wr*64 + ((lane >> 4) << 2);
#pragma unroll
    for (int mi = 0; mi < 4; ++mi) {
#pragma unroll
        for (int ni = 0; ni < 2; ++ni) {
            int c = colb + ni*16;
            if (c >= MS) continue;
#pragma unroll
            for (int j = 0; j < 4; ++j) {
                int r = rowb + mi*16 + j;
                if (r < MTOT)
                    S[((size_t)b*MTOT + r)*MS + c] = acc[mi][ni][j];
            }
        }
    }
}

// ---------------- K5a: row stats (gamma=20 softmax over 500 cols) ----------------
__global__ void k_rowstats(const float* __restrict__ S,
                           float* __restrict__ m20, float* __restrict__ rd20) {
    int row = blockIdx.x;
    int t = threadIdx.x;
    const float* r = S + (size_t)row*MS;
    float mx = -1e30f;
    for (int c = t; c < MS; c += 64) mx = fmaxf(mx, r[c]);
    for (int off = 32; off; off >>= 1) mx = fmaxf(mx, __shfl_xor(mx, off));
    float s = 0.f;
    for (int c = t; c < MS; c += 64) s += __expf(20.f*(r[c]-mx));
    for (int off = 32; off; off >>= 1) s += __shfl_xor(s, off);
    if (t == 0) { m20[row] = mx; rd20[row] = 1.0f/s; }
}

// ---------------- K5b: col stats (gamma2=10 softmax over 100 rows) ----------------
__global__ void k_colstats(const float* __restrict__ S,
                           float* __restrict__ m10, float* __restrict__ rd10) {
    int sys = blockIdx.x;
    int t = threadIdx.x;
    if (t >= MS) return;
    const float* base = S + (size_t)sys*MQ*MS + t;
    float mx = -1e30f;
    for (int i = 0; i < MQ; ++i) mx = fmaxf(mx, base[(size_t)i*MS]);
    float s = 0.f;
    for (int i = 0; i < MQ; ++i) s += __expf(10.f*(base[(size_t)i*MS]-mx));
    m10[sys*MS + t] = mx;
    rd10[sys*MS + t] = 1.0f/s;
}

// ---------------- K6: B[i][j] = sum_col P[i][col]*Q[j][col], rhs ----------------
#define KC 50
__global__ __launch_bounds__(256) void k_formB(
        const float* __restrict__ S,
        const float* __restrict__ m10, const float* __restrict__ rd10,
        const float* __restrict__ m20, const float* __restrict__ rd20,
        float* __restrict__ Bmat, float* __restrict__ rhs) {
    __shared__ float P[MQ][KC+4];
    __shared__ float Q[MQ][KC+4];
    int sys = blockIdx.x;
    int t = threadIdx.x;
    int tx = t % 25, ty = t / 25;     // ty<10 compute
    int i0 = tx*4, j0 = ty*10;
    float acc[4][10] = {};
    float rs = 0.f;
    const float* Sb   = S    + (size_t)sys*MQ*MS;
    const float* m10b = m10  + sys*MS;
    const float* r10b = rd10 + sys*MS;
    const float* m20b = m20  + sys*MQ;
    const float* r20b = rd20 + sys*MQ;

    for (int col0 = 0; col0 < MS; col0 += KC) {
        __syncthreads();
        for (int l = t; l < MQ*KC; l += 256) {
            int r = l / KC, cc = l % KC;
            float v = Sb[(size_t)r*MS + col0 + cc];
            P[r][cc] = __expf(10.f*(v - m10b[col0+cc])) * r10b[col0+cc];
            Q[r][cc] = __expf(20.f*(v - m20b[r])) * r20b[r];
        }
        __syncthreads();
        if (t < MQ) {
#pragma unroll
            for (int cc = 0; cc < KC; ++cc) rs += P[t][cc];
        }
        if (ty < 10) {
            for (int c2 = 0; c2 < KC; c2 += 2) {
                float2 p0 = *(const float2*)&P[i0+0][c2];
                float2 p1 = *(const float2*)&P[i0+1][c2];
                float2 p2 = *(const float2*)&P[i0+2][c2];
                float2 p3 = *(const float2*)&P[i0+3][c2];
#pragma unroll
                for (int jj = 0; jj < 10; ++jj) {
                    float2 qv = *(const float2*)&Q[j0+jj][c2];
                    acc[0][jj] += p0.x*qv.x + p0.y*qv.y;
                    acc[1][jj] += p1.x*qv.x + p1.y*qv.y;
                    acc[2][jj] += p2.x*qv.x + p2.y*qv.y;
                    acc[3][jj] += p3.x*qv.x + p3.y*qv.y;
                }
            }
        }
    }
    if (ty < 10) {
#pragma unroll
        for (int r = 0; r < 4; ++r)
#pragma unroll
            for (int jj = 0; jj < 10; ++jj)
                Bmat[(size_t)sys*MQ*MQ + (size_t)(i0+r)*MQ + j0+jj] = acc[r][jj];
    }
    if (t < MQ) rhs[sys*MQ + t] = 1.0f + 0.5f*rs;
}

// ---------------- K7: Jacobi solve (I - 0.25 B) x = rhs, normalize ----------------
__global__ __launch_bounds__(128) void k_solve(
        const float* __restrict__ Bmat, const float* __restrict__ rhs,
        float* __restrict__ out) {
    __shared__ float Bsh[MQ][MQ+1];
    __shared__ float xs[MQ];
    __shared__ float rh[MQ];
    __shared__ float partial[2];
    int sys = blockIdx.x;
    int t = threadIdx.x;
    const float* Bg = Bmat + (size_t)sys*MQ*MQ;
    for (int l = t; l < MQ*MQ; l += 128) Bsh[l/MQ][l%MQ] = Bg[l];
    if (t < MQ) { rh[t] = rhs[sys*MQ+t]; xs[t] = rh[t]; }
    __syncthreads();
    for (int it = 0; it < 30; ++it) {
        float s = 0.f;
        if (t < MQ) {
            for (int j = 0; j < MQ; ++j) s += Bsh[t][j]*xs[j];
        }
        __syncthreads();
        if (t < MQ) xs[t] = rh[t] + 0.25f*s;
        __syncthreads();
    }
    float kv = (t < MQ) ? (xs[t] - 1.0f) : 0.f;
    float s = kv;
    for (int off = 32; off; off >>= 1) s += __shfl_xor(s, off);
    if ((t & 63) == 0) partial[t >> 6] = s;
    __syncthreads();
    float tot = partial[0] + partial[1];
    if (t < MQ) out[sys*MQ + t] = kv / tot;
}

extern "C" void kernel_launch(void* const* d_in, const int* in_sizes, int n_in,
                              void* d_out, int out_size, void* d_ws, size_t ws_size,
                              hipStream_t stream) {
    const float* sup = (const float*)d_in[0];
    const float* qry = (const float*)d_in[1];
    float* out = (float*)d_out;
    float* ws  = (float*)d_ws;

    float* supmean = ws;                        // 1,280,000 f
    float* invs    = supmean + 1280000;         // 2,000
    float* invq    = invs + 2000;               // 30,000
    float* Smat    = invq + 30000;              // 15,000,000
    float* m20     = Smat + 15000000;           // 30,000
    float* rd20    = m20 + 30000;               // 30,000
    float* m10     = rd20 + 30000;              // 150,000
    float* rd10    = m10 + 150000;              // 150,000
    float* Bm      = rd10 + 150000;             // 3,000,000
    float* rh      = Bm + 3000000;              // 30,000
    ushort* Ahh    = (ushort*)(rh + 30000);     // 19,200,000 u16
    ushort* All    = Ahh + 19200000;            // 19,200,000
    ushort* Bhh    = All + 19200000;            // 1,280,000
    ushort* Bll    = Bhh + 1280000;             // 1,280,000

    k_supmean<<<(BATCH*NWAY*CH*HW + 255)/256, 256, 0, stream>>>(sup, supmean);
    k_invnorm<<<BATCH*NWAY, 128, 0, stream>>>(supmean, invs);
    k_invnorm<<<BATCH*NQ, 128, 0, stream>>>(qry, invq);
    k_prep<<<dim3(10, 2, BATCH*NQ),   256, 0, stream>>>(qry,     invq, Ahh, All);
    k_prep<<<dim3(10, 2, BATCH*NWAY), 256, 0, stream>>>(supmean, invs, Bhh, Bll);
    k_gemm<<<dim3(8, 59, BATCH), 256, 0, stream>>>(Ahh, All, Bhh, Bll, Smat);
    k_rowstats<<<NSYS*MQ, 64, 0, stream>>>(Smat, m20, rd20);
    k_colstats<<<NSYS, 512, 0, stream>>>(Smat, m10, rd10);
    k_formB<<<NSYS, 256, 0, stream>>>(Smat, m10, rd10, m20, rd20, Bm, rh);
    k_solve<<<NSYS, 128, 0, stream>>>(Bm, rh, out);
}

// Round 3
// 399.017 us; speedup vs baseline: 1.4799x; 1.2266x over previous
//
#include <hip/hip_runtime.h>
#include <math.h>

#define BATCH 4
#define NSUP 25
#define NQ   75
#define CH   640
#define HW   100
#define NWAY 5
#define KSHOT 5
#define NSYS (BATCH*NQ)   // 300
#define MS   (NWAY*HW)    // 500
#define MQ   HW           // 100
#define MTOT (NQ*HW)      // 7500 rows per batch

typedef __attribute__((ext_vector_type(8))) short bf16x8;
typedef __attribute__((ext_vector_type(4))) float f32x4;

__device__ __forceinline__ ushort f2bf(float f) {
    unsigned u = __float_as_uint(f);
    u += 0x7fff + ((u >> 16) & 1);          // RNE
    return (ushort)(u >> 16);
}
__device__ __forceinline__ float bf2f(ushort h) {
    return __uint_as_float(((unsigned)h) << 16);
}

#define GLD_LDS16(gp, lp) __builtin_amdgcn_global_load_lds( \
    (const __attribute__((address_space(1))) unsigned*)(const void*)(gp), \
    (__attribute__((address_space(3))) unsigned*)(void*)(lp), 16, 0, 0)

// ---------------- K1: class mean of support ----------------
__global__ void k_supmean(const float* __restrict__ sup, float* __restrict__ supmean) {
    int idx = blockIdx.x * 256 + threadIdx.x;
    if (idx >= BATCH*NWAY*CH*HW) return;
    int m = idx % HW;
    int c = (idx / HW) % CH;
    int n = (idx / (HW*CH)) % NWAY;
    int b = idx / (HW*CH*NWAY);
    const float* base = sup + (((size_t)(b*NSUP + n*KSHOT)*CH + c)*HW + m);
    float acc = 0.f;
#pragma unroll
    for (int k = 0; k < KSHOT; ++k) acc += base[(size_t)k*CH*HW];
    supmean[idx] = acc * 0.2f;
}

// ---------------- K2: inverse column norms over channel axis ----------------
__global__ void k_invnorm(const float* __restrict__ in, float* __restrict__ inv) {
    int p = blockIdx.x;
    int t = threadIdx.x;
    if (t >= HW) return;
    const float* base = in + (size_t)p*CH*HW + t;
    float acc = 0.f;
    for (int c = 0; c < CH; ++c) { float v = base[(size_t)c*HW]; acc += v*v; }
    inv[p*HW + t] = 1.0f / (1e-16f + sqrtf(acc));
}

// ---------------- K3: transpose + normalize + bf16 hi/lo split ----------------
__global__ __launch_bounds__(256) void k_prep(const float* __restrict__ in,
        const float* __restrict__ inv, ushort* __restrict__ hi, ushort* __restrict__ lo) {
    __shared__ float tile[64][65];
    int p  = blockIdx.z;
    int c0 = blockIdx.x * 64;
    int m0 = blockIdx.y * 64;
    int t  = threadIdx.x;
    const float* ib = in + (size_t)p*CH*HW;
#pragma unroll
    for (int i = 0; i < 16; ++i) {
        int l = i*256 + t;
        int cl = l >> 6, ml = l & 63;
        int m = m0 + ml;
        tile[cl][ml] = (m < HW) ? ib[(size_t)(c0+cl)*HW + m] : 0.f;
    }
    __syncthreads();
#pragma unroll
    for (int i = 0; i < 16; ++i) {
        int l = i*256 + t;
        int ml = l >> 6, cl = l & 63;
        int m = m0 + ml;
        if (m < HW) {
            size_t r = (size_t)p*HW + m;
            float v = tile[cl][ml] * inv[r];
            ushort h = f2bf(v);
            float fl = v - bf2f(h);
            hi[r*CH + c0 + cl] = h;
            lo[r*CH + c0 + cl] = f2bf(fl);
        }
    }
}

// ---------------- K4: split-bf16 MFMA GEMM  S = A * B^T ----------------
#define BM 128
#define BN 64
#define BK 64
#define NKT (CH/BK)
__global__ __launch_bounds__(256) void k_gemm(
        const ushort* __restrict__ Ah, const ushort* __restrict__ Al,
        const ushort* __restrict__ Bh, const ushort* __restrict__ Bl,
        float* __restrict__ S) {
    __shared__ __align__(1024) char lds[49152];
    int b  = blockIdx.z;
    int rt = blockIdx.y;
    int ct = blockIdx.x;
    int t  = threadIdx.x;
    int lane = t & 63, w = t >> 6;
    int row0 = rt * BM, col0 = ct * BN;

    size_t aoff[4]; size_t boff[2];
    int lbase[4];
#pragma unroll
    for (int i = 0; i < 4; ++i) {
        int X = i*4096 + t*16;
        int L = X ^ (((X >> 7) & 7) << 4);
        int row = L >> 7;
        int kb  = L & 127;
        int gr = row0 + row; if (gr > MTOT-1) gr = MTOT-1;
        aoff[i] = ((size_t)b*MTOT + gr)*CH + (kb >> 1);
        lbase[i] = i*4096 + (w << 10);
    }
#pragma unroll
    for (int i = 0; i < 2; ++i) {
        int X = i*4096 + t*16;
        int L = X ^ (((X >> 7) & 7) << 4);
        int col = L >> 7;
        int kb  = L & 127;
        int gc = col0 + col; if (gc > MS-1) gc = MS-1;
        boff[i] = ((size_t)b*MS + gc)*CH + (kb >> 1);
    }

    f32x4 acc[4][2];
#pragma unroll
    for (int mi = 0; mi < 4; ++mi)
#pragma unroll
        for (int ni = 0; ni < 2; ++ni) acc[mi][ni] = (f32x4){0.f,0.f,0.f,0.f};

    int wr = w >> 1, wc = w & 1;
    const char* AHl = lds;
    const char* ALl = lds + 16384;
    const char* BHl = lds + 32768;
    const char* BLl = lds + 40960;

    for (int kt = 0; kt < NKT; ++kt) {
        size_t ka = (size_t)kt * BK;
#pragma unroll
        for (int i = 0; i < 4; ++i) {
            GLD_LDS16(Ah + aoff[i] + ka, lds + lbase[i]);
            GLD_LDS16(Al + aoff[i] + ka, lds + 16384 + lbase[i]);
        }
#pragma unroll
        for (int i = 0; i < 2; ++i) {
            GLD_LDS16(Bh + boff[i] + ka, lds + 32768 + lbase[i]);
            GLD_LDS16(Bl + boff[i] + ka, lds + 40960 + lbase[i]);
        }
        __syncthreads();
        int kg = lane >> 4;
#pragma unroll
        for (int ks = 0; ks < 2; ++ks) {
            bf16x8 bh[2], bl[2];
#pragma unroll
            for (int ni = 0; ni < 2; ++ni) {
                int colr = wc*32 + ni*16 + (lane & 15);
                int L = colr*128 + ks*64 + kg*16;
                int P = L ^ ((colr & 7) << 4);
                bh[ni] = *(const bf16x8*)(BHl + P);
                bl[ni] = *(const bf16x8*)(BLl + P);
            }
#pragma unroll
            for (int mi = 0; mi < 4; ++mi) {
                int rowr = wr*64 + mi*16 + (lane & 15);
                int L = rowr*128 + ks*64 + kg*16;
                int P = L ^ ((rowr & 7) << 4);
                bf16x8 ah = *(const bf16x8*)(AHl + P);
                bf16x8 al = *(const bf16x8*)(ALl + P);
#pragma unroll
                for (int ni = 0; ni < 2; ++ni) {
                    acc[mi][ni] = __builtin_amdgcn_mfma_f32_16x16x32_bf16(ah, bh[ni], acc[mi][ni], 0, 0, 0);
                    acc[mi][ni] = __builtin_amdgcn_mfma_f32_16x16x32_bf16(ah, bl[ni], acc[mi][ni], 0, 0, 0);
                    acc[mi][ni] = __builtin_amdgcn_mfma_f32_16x16x32_bf16(al, bh[ni], acc[mi][ni], 0, 0, 0);
                }
            }
        }
        __syncthreads();
    }
    int colb = col0 + wc*32 + (lane & 15);
    int rowb = row0 + wr*64 + ((lane >> 4) << 2);
#pragma unroll
    for (int mi = 0; mi < 4; ++mi) {
#pragma unroll
        for (int ni = 0; ni < 2; ++ni) {
            int c = colb + ni*16;
            if (c >= MS) continue;
#pragma unroll
            for (int j = 0; j < 4; ++j) {
                int r = rowb + mi*16 + j;
                if (r < MTOT)
                    S[((size_t)b*MTOT + r)*MS + c] = acc[mi][ni][j];
            }
        }
    }
}

// ---------------- K5a: row stats (gamma=20 softmax over 500 cols) ----------------
__global__ void k_rowstats(const float* __restrict__ S,
                           float* __restrict__ m20, float* __restrict__ rd20) {
    int row = blockIdx.x;
    int t = threadIdx.x;
    const float* r = S + (size_t)row*MS;
    float mx = -1e30f;
    for (int c = t; c < MS; c += 64) mx = fmaxf(mx, r[c]);
    for (int off = 32; off; off >>= 1) mx = fmaxf(mx, __shfl_xor(mx, off));
    float s = 0.f;
    for (int c = t; c < MS; c += 64) s += __expf(20.f*(r[c]-mx));
    for (int off = 32; off; off >>= 1) s += __shfl_xor(s, off);
    if (t == 0) { m20[row] = mx; rd20[row] = 1.0f/s; }
}

// ---------------- K5b: col stats (gamma2=10 softmax over 100 rows) ----------------
__global__ void k_colstats(const float* __restrict__ S,
                           float* __restrict__ m10, float* __restrict__ rd10) {
    int sys = blockIdx.x;
    int t = threadIdx.x;
    if (t >= MS) return;
    const float* base = S + (size_t)sys*MQ*MS + t;
    float mx = -1e30f;
    for (int i = 0; i < MQ; ++i) mx = fmaxf(mx, base[(size_t)i*MS]);
    float s = 0.f;
    for (int i = 0; i < MQ; ++i) s += __expf(10.f*(base[(size_t)i*MS]-mx));
    m10[sys*MS + t] = mx;
    rd10[sys*MS + t] = 1.0f/s;
}

// ---------------- K6: partial B over a 100-col slice, reg accumulation ----------------
// B[i][j] = sum_c P[i][c]*Q[j][c];  P = T_qs^T (col-softmax g10), Q = T_sq (row-softmax g20)
// grid (5, 300): part p covers cols [p*100, p*100+100) as 2 sub-chunks of 50.
#define KC 50
#define NCH 2
#define NPART 5
#define PADP 102
__global__ __launch_bounds__(256) void k_formB_part(
        const float* __restrict__ S,
        const float* __restrict__ m10, const float* __restrict__ rd10,
        const float* __restrict__ m20, const float* __restrict__ rd20,
        float* __restrict__ Bpart, float* __restrict__ rspart) {
    __shared__ float PT[KC][PADP];   // PT[c][i] = P[i][col0+c]
    __shared__ float QT[KC][PADP];   // QT[c][j] = Q[j][col0+c]
    __shared__ float m20s[MQ], r20s[MQ];
    int part = blockIdx.x;
    int sys  = blockIdx.y;
    int t = threadIdx.x;
    int tx = t % 25, ty = t / 25;    // ty<10 compute; tx -> 4 cols j, ty -> 10 rows i
    int j0 = tx*4, i0 = ty*10;
    float acc[10][4] = {};
    float rs = 0.f;
    const float* Sb   = S    + (size_t)sys*MQ*MS;
    const float* m10b = m10  + sys*MS;
    const float* r10b = rd10 + sys*MS;
    if (t < MQ) { m20s[t] = m20[sys*MQ+t]; r20s[t] = rd20[sys*MQ+t]; }

    for (int sub = 0; sub < NCH; ++sub) {
        int col0 = part*(KC*NCH) + sub*KC;
        __syncthreads();
        for (int l = t; l < MQ*KC; l += 256) {
            int r = l / KC, c = l % KC;
            float v = Sb[(size_t)r*MS + col0 + c];
            PT[c][r] = __expf(10.f*(v - m10b[col0+c])) * r10b[col0+c];
            QT[c][r] = __expf(20.f*(v - m20s[r])) * r20s[r];
        }
        __syncthreads();
        if (t < MQ) {
#pragma unroll
            for (int c = 0; c < KC; ++c) rs += PT[c][t];
        }
        if (ty < 10) {
            for (int c = 0; c < KC; ++c) {
                float2 q01 = *(const float2*)&QT[c][j0];
                float2 q23 = *(const float2*)&QT[c][j0+2];
                float2 p[5];
#pragma unroll
                for (int u = 0; u < 5; ++u) p[u] = *(const float2*)&PT[c][i0+2*u];
#pragma unroll
                for (int u = 0; u < 5; ++u) {
                    acc[2*u  ][0] += p[u].x*q01.x; acc[2*u  ][1] += p[u].x*q01.y;
                    acc[2*u  ][2] += p[u].x*q23.x; acc[2*u  ][3] += p[u].x*q23.y;
                    acc[2*u+1][0] += p[u].y*q01.x; acc[2*u+1][1] += p[u].y*q01.y;
                    acc[2*u+1][2] += p[u].y*q23.x; acc[2*u+1][3] += p[u].y*q23.y;
                }
            }
        }
    }
    if (ty < 10) {
        float* Bp = Bpart + ((size_t)part*NSYS + sys)*(MQ*MQ);
#pragma unroll
        for (int ii = 0; ii < 10; ++ii) {
            float4 v = make_float4(acc[ii][0], acc[ii][1], acc[ii][2], acc[ii][3]);
            *(float4*)&Bp[(i0+ii)*MQ + j0] = v;
        }
    }
    if (t < MQ) rspart[((size_t)part*NSYS + sys)*MQ + t] = rs;
}

// ---------------- K7: sum partials, Jacobi solve (I - 0.25 B) x = rhs, normalize ----------------
__global__ __launch_bounds__(256) void k_solve(
        const float* __restrict__ Bpart, const float* __restrict__ rspart,
        float* __restrict__ out) {
    __shared__ float Bsh[MQ][MQ+1];
    __shared__ float xs[MQ];
    __shared__ float rh[MQ];
    __shared__ float partial[4];
    int sys = blockIdx.x;
    int t = threadIdx.x;
    for (int l = t; l < MQ*MQ; l += 256) {
        float s = 0.f;
#pragma unroll
        for (int p = 0; p < NPART; ++p)
            s += Bpart[((size_t)p*NSYS + sys)*(MQ*MQ) + l];
        Bsh[l/MQ][l%MQ] = s;
    }
    if (t < MQ) {
        float rsum = 0.f;
#pragma unroll
        for (int p = 0; p < NPART; ++p)
            rsum += rspart[((size_t)p*NSYS + sys)*MQ + t];
        rh[t] = 1.0f + 0.5f*rsum;
        xs[t] = rh[t];
    }
    __syncthreads();
    for (int it = 0; it < 30; ++it) {
        float s = 0.f;
        if (t < MQ) {
            for (int j = 0; j < MQ; ++j) s += Bsh[t][j]*xs[j];
        }
        __syncthreads();
        if (t < MQ) xs[t] = rh[t] + 0.25f*s;
        __syncthreads();
    }
    float kv = (t < MQ) ? (xs[t] - 1.0f) : 0.f;
    float s = kv;
    for (int off = 32; off; off >>= 1) s += __shfl_xor(s, off);
    if ((t & 63) == 0) partial[t >> 6] = s;
    __syncthreads();
    float tot = partial[0] + partial[1] + partial[2] + partial[3];
    if (t < MQ) out[sys*MQ + t] = kv / tot;
}

extern "C" void kernel_launch(void* const* d_in, const int* in_sizes, int n_in,
                              void* d_out, int out_size, void* d_ws, size_t ws_size,
                              hipStream_t stream) {
    const float* sup = (const float*)d_in[0];
    const float* qry = (const float*)d_in[1];
    float* out = (float*)d_out;
    float* ws  = (float*)d_ws;

    float* supmean = ws;                        // 1,280,000 f
    float* invs    = supmean + 1280000;         // 2,000
    float* invq    = invs + 2000;               // 30,000
    float* Smat    = invq + 30000;              // 15,000,000
    float* m20     = Smat + 15000000;           // 30,000
    float* rd20    = m20 + 30000;               // 30,000
    float* m10     = rd20 + 30000;              // 150,000
    float* rd10    = m10 + 150000;              // 150,000
    float* Bm      = rd10 + 150000;             // 3,000,000 (unused now, kept for layout)
    float* rh      = Bm + 3000000;              // 30,000
    ushort* Ahh    = (ushort*)(rh + 30000);     // 19,200,000 u16
    ushort* All    = Ahh + 19200000;            // 19,200,000
    ushort* Bhh    = All + 19200000;            // 1,280,000
    ushort* Bll    = Bhh + 1280000;             // 1,280,000
    // Bpart/rspart alias the A-split arrays (dead after k_gemm): 15.15M floats < 19.2M
    float* Bpart   = (float*)Ahh;               // 15,000,000 f
    float* rspart  = Bpart + 15000000;          // 150,000 f

    k_supmean<<<(BATCH*NWAY*CH*HW + 255)/256, 256, 0, stream>>>(sup, supmean);
    k_invnorm<<<BATCH*NWAY, 128, 0, stream>>>(supmean, invs);
    k_invnorm<<<BATCH*NQ, 128, 0, stream>>>(qry, invq);
    k_prep<<<dim3(10, 2, BATCH*NQ),   256, 0, stream>>>(qry,     invq, Ahh, All);
    k_prep<<<dim3(10, 2, BATCH*NWAY), 256, 0, stream>>>(supmean, invs, Bhh, Bll);
    k_gemm<<<dim3(8, 59, BATCH), 256, 0, stream>>>(Ahh, All, Bhh, Bll, Smat);
    k_rowstats<<<NSYS*MQ, 64, 0, stream>>>(Smat, m20, rd20);
    k_colstats<<<NSYS, 512, 0, stream>>>(Smat, m10, rd10);
    k_formB_part<<<dim3(NPART, NSYS), 256, 0, stream>>>(Smat, m10, rd10, m20, rd20, Bpart, rspart);
    k_solve<<<NSYS, 256, 0, stream>>>(Bpart, rspart, out);
}

// Round 4
// 315.969 us; speedup vs baseline: 1.8689x; 1.2628x over previous
//
#include <hip/hip_runtime.h>
#include <math.h>

#define BATCH 4
#define NSUP 25
#define NQ   75
#define CH   640
#define HW   100
#define NWAY 5
#define KSHOT 5
#define NSYS (BATCH*NQ)   // 300
#define MS   (NWAY*HW)    // 500
#define MQ   HW           // 100
#define MTOT (NQ*HW)      // 7500 rows per batch

typedef __attribute__((ext_vector_type(8))) short bf16x8;
typedef __attribute__((ext_vector_type(4))) float f32x4;

__device__ __forceinline__ ushort f2bf(float f) {
    unsigned u = __float_as_uint(f);
    u += 0x7fff + ((u >> 16) & 1);          // RNE
    return (ushort)(u >> 16);
}
__device__ __forceinline__ float bf2f(ushort h) {
    return __uint_as_float(((unsigned)h) << 16);
}

#define GLD_LDS16(gp, lp) __builtin_amdgcn_global_load_lds( \
    (const __attribute__((address_space(1))) unsigned*)(const void*)(gp), \
    (__attribute__((address_space(3))) unsigned*)(void*)(lp), 16, 0, 0)

// ---------------- K1: class mean of support ----------------
__global__ void k_supmean(const float* __restrict__ sup, float* __restrict__ supmean) {
    int idx = blockIdx.x * 256 + threadIdx.x;
    if (idx >= BATCH*NWAY*CH*HW) return;
    int m = idx % HW;
    int c = (idx / HW) % CH;
    int n = (idx / (HW*CH)) % NWAY;
    int b = idx / (HW*CH*NWAY);
    const float* base = sup + (((size_t)(b*NSUP + n*KSHOT)*CH + c)*HW + m);
    float acc = 0.f;
#pragma unroll
    for (int k = 0; k < KSHOT; ++k) acc += base[(size_t)k*CH*HW];
    supmean[idx] = acc * 0.2f;
}

// ---------------- K2: inverse column norms over channel axis ----------------
__global__ void k_invnorm(const float* __restrict__ in, float* __restrict__ inv) {
    int p = blockIdx.x;
    int t = threadIdx.x;
    if (t >= HW) return;
    const float* base = in + (size_t)p*CH*HW + t;
    float acc = 0.f;
    for (int c = 0; c < CH; ++c) { float v = base[(size_t)c*HW]; acc += v*v; }
    inv[p*HW + t] = 1.0f / (1e-16f + sqrtf(acc));
}

// ---------------- K3: transpose + normalize + bf16 hi/lo split ----------------
__global__ __launch_bounds__(256) void k_prep(const float* __restrict__ in,
        const float* __restrict__ inv, ushort* __restrict__ hi, ushort* __restrict__ lo) {
    __shared__ float tile[64][65];
    int p  = blockIdx.z;
    int c0 = blockIdx.x * 64;
    int m0 = blockIdx.y * 64;
    int t  = threadIdx.x;
    const float* ib = in + (size_t)p*CH*HW;
#pragma unroll
    for (int i = 0; i < 16; ++i) {
        int l = i*256 + t;
        int cl = l >> 6, ml = l & 63;
        int m = m0 + ml;
        tile[cl][ml] = (m < HW) ? ib[(size_t)(c0+cl)*HW + m] : 0.f;
    }
    __syncthreads();
#pragma unroll
    for (int i = 0; i < 16; ++i) {
        int l = i*256 + t;
        int ml = l >> 6, cl = l & 63;
        int m = m0 + ml;
        if (m < HW) {
            size_t r = (size_t)p*HW + m;
            float v = tile[cl][ml] * inv[r];
            ushort h = f2bf(v);
            float fl = v - bf2f(h);
            hi[r*CH + c0 + cl] = h;
            lo[r*CH + c0 + cl] = f2bf(fl);
        }
    }
}

// ---------------- K4: split-bf16 MFMA GEMM  S = A * B^T ----------------
// XCD-swizzled flat grid: ct fastest within a same-XCD chunk so the 8
// column-tiles sharing one A row-panel hit the same XCD's L2.
#define BM 128
#define BN 64
#define BK 64
#define NKT (CH/BK)
#define NCT 8
#define NRT 59
#define NWG (NCT*NRT*BATCH)   // 1888, divisible by 8
__global__ __launch_bounds__(256) void k_gemm(
        const ushort* __restrict__ Ah, const ushort* __restrict__ Al,
        const ushort* __restrict__ Bh, const ushort* __restrict__ Bl,
        float* __restrict__ S) {
    __shared__ __align__(1024) char lds[49152];
    int hwid = blockIdx.x;
    int l = (hwid & 7) * (NWG/8) + (hwid >> 3);   // chunked XCD swizzle
    int ct = l & 7;
    int rt = (l >> 3) % NRT;
    int b  = l / (NCT*NRT);
    int t  = threadIdx.x;
    int lane = t & 63, w = t >> 6;
    int row0 = rt * BM, col0 = ct * BN;

    size_t aoff[4]; size_t boff[2];
    int lbase[4];
#pragma unroll
    for (int i = 0; i < 4; ++i) {
        int X = i*4096 + t*16;
        int L = X ^ (((X >> 7) & 7) << 4);
        int row = L >> 7;
        int kb  = L & 127;
        int gr = row0 + row; if (gr > MTOT-1) gr = MTOT-1;
        aoff[i] = ((size_t)b*MTOT + gr)*CH + (kb >> 1);
        lbase[i] = i*4096 + (w << 10);
    }
#pragma unroll
    for (int i = 0; i < 2; ++i) {
        int X = i*4096 + t*16;
        int L = X ^ (((X >> 7) & 7) << 4);
        int col = L >> 7;
        int kb  = L & 127;
        int gc = col0 + col; if (gc > MS-1) gc = MS-1;
        boff[i] = ((size_t)b*MS + gc)*CH + (kb >> 1);
    }

    f32x4 acc[4][2];
#pragma unroll
    for (int mi = 0; mi < 4; ++mi)
#pragma unroll
        for (int ni = 0; ni < 2; ++ni) acc[mi][ni] = (f32x4){0.f,0.f,0.f,0.f};

    int wr = w >> 1, wc = w & 1;
    const char* AHl = lds;
    const char* ALl = lds + 16384;
    const char* BHl = lds + 32768;
    const char* BLl = lds + 40960;

    for (int kt = 0; kt < NKT; ++kt) {
        size_t ka = (size_t)kt * BK;
#pragma unroll
        for (int i = 0; i < 4; ++i) {
            GLD_LDS16(Ah + aoff[i] + ka, lds + lbase[i]);
            GLD_LDS16(Al + aoff[i] + ka, lds + 16384 + lbase[i]);
        }
#pragma unroll
        for (int i = 0; i < 2; ++i) {
            GLD_LDS16(Bh + boff[i] + ka, lds + 32768 + lbase[i]);
            GLD_LDS16(Bl + boff[i] + ka, lds + 40960 + lbase[i]);
        }
        __syncthreads();
        int kg = lane >> 4;
#pragma unroll
        for (int ks = 0; ks < 2; ++ks) {
            bf16x8 bh[2], bl[2];
#pragma unroll
            for (int ni = 0; ni < 2; ++ni) {
                int colr = wc*32 + ni*16 + (lane & 15);
                int L = colr*128 + ks*64 + kg*16;
                int P = L ^ ((colr & 7) << 4);
                bh[ni] = *(const bf16x8*)(BHl + P);
                bl[ni] = *(const bf16x8*)(BLl + P);
            }
#pragma unroll
            for (int mi = 0; mi < 4; ++mi) {
                int rowr = wr*64 + mi*16 + (lane & 15);
                int L = rowr*128 + ks*64 + kg*16;
                int P = L ^ ((rowr & 7) << 4);
                bf16x8 ah = *(const bf16x8*)(AHl + P);
                bf16x8 al = *(const bf16x8*)(ALl + P);
#pragma unroll
                for (int ni = 0; ni < 2; ++ni) {
                    acc[mi][ni] = __builtin_amdgcn_mfma_f32_16x16x32_bf16(ah, bh[ni], acc[mi][ni], 0, 0, 0);
                    acc[mi][ni] = __builtin_amdgcn_mfma_f32_16x16x32_bf16(ah, bl[ni], acc[mi][ni], 0, 0, 0);
                    acc[mi][ni] = __builtin_amdgcn_mfma_f32_16x16x32_bf16(al, bh[ni], acc[mi][ni], 0, 0, 0);
                }
            }
        }
        __syncthreads();
    }
    int colb = col0 + wc*32 + (lane & 15);
    int rowb = row0 + wr*64 + ((lane >> 4) << 2);
#pragma unroll
    for (int mi = 0; mi < 4; ++mi) {
#pragma unroll
        for (int ni = 0; ni < 2; ++ni) {
            int c = colb + ni*16;
            if (c >= MS) continue;
#pragma unroll
            for (int j = 0; j < 4; ++j) {
                int r = rowb + mi*16 + j;
                if (r < MTOT)
                    S[((size_t)b*MTOT + r)*MS + c] = acc[mi][ni][j];
            }
        }
    }
}

// ---------------- K5a: row stats (gamma=20 softmax over 500 cols) ----------------
__global__ void k_rowstats(const float* __restrict__ S,
                           float* __restrict__ m20, float* __restrict__ rd20) {
    int row = blockIdx.x;
    int t = threadIdx.x;
    const float* r = S + (size_t)row*MS;
    float mx = -1e30f;
    for (int c = t; c < MS; c += 64) mx = fmaxf(mx, r[c]);
    for (int off = 32; off; off >>= 1) mx = fmaxf(mx, __shfl_xor(mx, off));
    float s = 0.f;
    for (int c = t; c < MS; c += 64) s += __expf(20.f*(r[c]-mx));
    for (int off = 32; off; off >>= 1) s += __shfl_xor(s, off);
    if (t == 0) { m20[row] = mx; rd20[row] = 1.0f/s; }
}

// ---------------- K5b: col stats (gamma2=10 softmax over 100 rows) ----------------
__global__ void k_colstats(const float* __restrict__ S,
                           float* __restrict__ m10, float* __restrict__ rd10) {
    int sys = blockIdx.x;
    int t = threadIdx.x;
    if (t >= MS) return;
    const float* base = S + (size_t)sys*MQ*MS + t;
    float mx = -1e30f;
    for (int i = 0; i < MQ; ++i) mx = fmaxf(mx, base[(size_t)i*MS]);
    float s = 0.f;
    for (int i = 0; i < MQ; ++i) s += __expf(10.f*(base[(size_t)i*MS]-mx));
    m10[sys*MS + t] = mx;
    rd10[sys*MS + t] = 1.0f/s;
}

// ---------------- K6: partial B over a 100-col slice, reg accumulation ----------------
#define KC 50
#define NCH 2
#define NPART 5
#define PADP 102
__global__ __launch_bounds__(256) void k_formB_part(
        const float* __restrict__ S,
        const float* __restrict__ m10, const float* __restrict__ rd10,
        const float* __restrict__ m20, const float* __restrict__ rd20,
        float* __restrict__ Bpart, float* __restrict__ rspart) {
    __shared__ float PT[KC][PADP];   // PT[c][i] = P[i][col0+c]
    __shared__ float QT[KC][PADP];   // QT[c][j] = Q[j][col0+c]
    __shared__ float m20s[MQ], r20s[MQ];
    int part = blockIdx.x;
    int sys  = blockIdx.y;
    int t = threadIdx.x;
    int tx = t % 25, ty = t / 25;
    int j0 = tx*4, i0 = ty*10;
    float acc[10][4] = {};
    float rs = 0.f;
    const float* Sb   = S    + (size_t)sys*MQ*MS;
    const float* m10b = m10  + sys*MS;
    const float* r10b = rd10 + sys*MS;
    if (t < MQ) { m20s[t] = m20[sys*MQ+t]; r20s[t] = rd20[sys*MQ+t]; }

    for (int sub = 0; sub < NCH; ++sub) {
        int col0 = part*(KC*NCH) + sub*KC;
        __syncthreads();
        for (int l = t; l < MQ*KC; l += 256) {
            int r = l / KC, c = l % KC;
            float v = Sb[(size_t)r*MS + col0 + c];
            PT[c][r] = __expf(10.f*(v - m10b[col0+c])) * r10b[col0+c];
            QT[c][r] = __expf(20.f*(v - m20s[r])) * r20s[r];
        }
        __syncthreads();
        if (t < MQ) {
#pragma unroll
            for (int c = 0; c < KC; ++c) rs += PT[c][t];
        }
        if (ty < 10) {
            for (int c = 0; c < KC; ++c) {
                float2 q01 = *(const float2*)&QT[c][j0];
                float2 q23 = *(const float2*)&QT[c][j0+2];
                float2 p[5];
#pragma unroll
                for (int u = 0; u < 5; ++u) p[u] = *(const float2*)&PT[c][i0+2*u];
#pragma unroll
                for (int u = 0; u < 5; ++u) {
                    acc[2*u  ][0] += p[u].x*q01.x; acc[2*u  ][1] += p[u].x*q01.y;
                    acc[2*u  ][2] += p[u].x*q23.x; acc[2*u  ][3] += p[u].x*q23.y;
                    acc[2*u+1][0] += p[u].y*q01.x; acc[2*u+1][1] += p[u].y*q01.y;
                    acc[2*u+1][2] += p[u].y*q23.x; acc[2*u+1][3] += p[u].y*q23.y;
                }
            }
        }
    }
    if (ty < 10) {
        float* Bp = Bpart + ((size_t)part*NSYS + sys)*(MQ*MQ);
#pragma unroll
        for (int ii = 0; ii < 10; ++ii) {
            float4 v = make_float4(acc[ii][0], acc[ii][1], acc[ii][2], acc[ii][3]);
            *(float4*)&Bp[(i0+ii)*MQ + j0] = v;
        }
    }
    if (t < MQ) rspart[((size_t)part*NSYS + sys)*MQ + t] = rs;
}

// ---------------- K7: sum partials, Jacobi solve (I - 0.25 B) x = rhs, normalize ----------------
__global__ __launch_bounds__(256) void k_solve(
        const float* __restrict__ Bpart, const float* __restrict__ rspart,
        float* __restrict__ out) {
    __shared__ float Bsh[MQ][MQ+1];
    __shared__ float xs[MQ];
    __shared__ float rh[MQ];
    __shared__ float partial[4];
    int sys = blockIdx.x;
    int t = threadIdx.x;
    for (int l = t; l < MQ*MQ; l += 256) {
        float s = 0.f;
#pragma unroll
        for (int p = 0; p < NPART; ++p)
            s += Bpart[((size_t)p*NSYS + sys)*(MQ*MQ) + l];
        Bsh[l/MQ][l%MQ] = s;
    }
    if (t < MQ) {
        float rsum = 0.f;
#pragma unroll
        for (int p = 0; p < NPART; ++p)
            rsum += rspart[((size_t)p*NSYS + sys)*MQ + t];
        rh[t] = 1.0f + 0.5f*rsum;
        xs[t] = rh[t];
    }
    __syncthreads();
    for (int it = 0; it < 30; ++it) {
        float s = 0.f;
        if (t < MQ) {
            for (int j = 0; j < MQ; ++j) s += Bsh[t][j]*xs[j];
        }
        __syncthreads();
        if (t < MQ) xs[t] = rh[t] + 0.25f*s;
        __syncthreads();
    }
    float kv = (t < MQ) ? (xs[t] - 1.0f) : 0.f;
    float s = kv;
    for (int off = 32; off; off >>= 1) s += __shfl_xor(s, off);
    if ((t & 63) == 0) partial[t >> 6] = s;
    __syncthreads();
    float tot = partial[0] + partial[1] + partial[2] + partial[3];
    if (t < MQ) out[sys*MQ + t] = kv / tot;
}

extern "C" void kernel_launch(void* const* d_in, const int* in_sizes, int n_in,
                              void* d_out, int out_size, void* d_ws, size_t ws_size,
                              hipStream_t stream) {
    const float* sup = (const float*)d_in[0];
    const float* qry = (const float*)d_in[1];
    float* out = (float*)d_out;
    float* ws  = (float*)d_ws;

    float* supmean = ws;                        // 1,280,000 f
    float* invs    = supmean + 1280000;         // 2,000
    float* invq    = invs + 2000;               // 30,000
    float* Smat    = invq + 30000;              // 15,000,000
    float* m20     = Smat + 15000000;           // 30,000
    float* rd20    = m20 + 30000;               // 30,000
    float* m10     = rd20 + 30000;              // 150,000
    float* rd10    = m10 + 150000;              // 150,000
    float* Bm      = rd10 + 150000;             // 3,000,000 (unused, layout keeper)
    float* rh      = Bm + 3000000;              // 30,000
    ushort* Ahh    = (ushort*)(rh + 30000);     // 19,200,000 u16
    ushort* All    = Ahh + 19200000;            // 19,200,000
    ushort* Bhh    = All + 19200000;            // 1,280,000
    ushort* Bll    = Bhh + 1280000;             // 1,280,000
    float* Bpart   = (float*)Ahh;               // 15,000,000 f (aliases dead A-split)
    float* rspart  = Bpart + 15000000;          // 150,000 f

    k_supmean<<<(BATCH*NWAY*CH*HW + 255)/256, 256, 0, stream>>>(sup, supmean);
    k_invnorm<<<BATCH*NWAY, 128, 0, stream>>>(supmean, invs);
    k_invnorm<<<BATCH*NQ, 128, 0, stream>>>(qry, invq);
    k_prep<<<dim3(10, 2, BATCH*NQ),   256, 0, stream>>>(qry,     invq, Ahh, All);
    k_prep<<<dim3(10, 2, BATCH*NWAY), 256, 0, stream>>>(supmean, invs, Bhh, Bll);
    k_gemm<<<NWG, 256, 0, stream>>>(Ahh, All, Bhh, Bll, Smat);
    k_rowstats<<<NSYS*MQ, 64, 0, stream>>>(Smat, m20, rd20);
    k_colstats<<<NSYS, 512, 0, stream>>>(Smat, m10, rd10);
    k_formB_part<<<dim3(NPART, NSYS), 256, 0, stream>>>(Smat, m10, rd10, m20, rd20, Bpart, rspart);
    k_solve<<<NSYS, 256, 0, stream>>>(Bpart, rspart, out);
}

// Round 5
// 279.989 us; speedup vs baseline: 2.1091x; 1.1285x over previous
//
#include <hip/hip_runtime.h>
#include <math.h>

#define BATCH 4
#define NSUP 25
#define NQ   75
#define CH   640
#define HW   100
#define NWAY 5
#define KSHOT 5
#define NSYS (BATCH*NQ)   // 300
#define MS   (NWAY*HW)    // 500
#define MQ   HW           // 100
#define MTOT (NQ*HW)      // 7500 rows per batch

typedef __attribute__((ext_vector_type(8))) short bf16x8;
typedef __attribute__((ext_vector_type(4))) float f32x4;

__device__ __forceinline__ ushort f2bf(float f) {
    unsigned u = __float_as_uint(f);
    u += 0x7fff + ((u >> 16) & 1);          // RNE
    return (ushort)(u >> 16);
}
__device__ __forceinline__ float bf2f(ushort h) {
    return __uint_as_float(((unsigned)h) << 16);
}

#define GLD_LDS16(gp, lp) __builtin_amdgcn_global_load_lds( \
    (const __attribute__((address_space(1))) unsigned*)(const void*)(gp), \
    (__attribute__((address_space(3))) unsigned*)(void*)(lp), 16, 0, 0)

// ---------------- K1: class mean of support ----------------
__global__ void k_supmean(const float* __restrict__ sup, float* __restrict__ supmean) {
    int idx = blockIdx.x * 256 + threadIdx.x;
    if (idx >= BATCH*NWAY*CH*HW) return;
    int m = idx % HW;
    int c = (idx / HW) % CH;
    int n = (idx / (HW*CH)) % NWAY;
    int b = idx / (HW*CH*NWAY);
    const float* base = sup + (((size_t)(b*NSUP + n*KSHOT)*CH + c)*HW + m);
    float acc = 0.f;
#pragma unroll
    for (int k = 0; k < KSHOT; ++k) acc += base[(size_t)k*CH*HW];
    supmean[idx] = acc * 0.2f;
}

// ---------------- K3: transpose + raw bf16 hi/lo split + norm partials ----------------
// in: [planes][CH][HW] fp32 -> hi/lo: [plane*HW + m][CH] bf16 (RAW values),
// normpart[cblk][plane*HW + m] = partial sum of squares over this 64-c block.
__global__ __launch_bounds__(256) void k_prep(const float* __restrict__ in,
        ushort* __restrict__ hi, ushort* __restrict__ lo,
        float* __restrict__ normpart, int planesHW) {
    __shared__ float tile[64][65];
    int p  = blockIdx.z;
    int c0 = blockIdx.x * 64;
    int m0 = blockIdx.y * 64;
    int t  = threadIdx.x;
    const float* ib = in + (size_t)p*CH*HW;
#pragma unroll
    for (int i = 0; i < 16; ++i) {
        int l = i*256 + t;
        int cl = l >> 6, ml = l & 63;
        int m = m0 + ml;
        tile[cl][ml] = (m < HW) ? ib[(size_t)(c0+cl)*HW + m] : 0.f;
    }
    __syncthreads();
    if (t < 64 && (m0 + t) < HW) {
        float s = 0.f;
#pragma unroll
        for (int cl = 0; cl < 64; ++cl) { float v = tile[cl][t]; s += v*v; }
        normpart[(size_t)blockIdx.x*planesHW + p*HW + m0 + t] = s;
    }
#pragma unroll
    for (int i = 0; i < 16; ++i) {
        int l = i*256 + t;
        int ml = l >> 6, cl = l & 63;
        int m = m0 + ml;
        if (m < HW) {
            size_t r = (size_t)p*HW + m;
            float v = tile[cl][ml];
            ushort h = f2bf(v);
            float fl = v - bf2f(h);
            hi[r*CH + c0 + cl] = h;
            lo[r*CH + c0 + cl] = f2bf(fl);
        }
    }
}

// ---------------- K3b: finish inverse norms ----------------
__global__ void k_finishinv(const float* __restrict__ part, float* __restrict__ inv, int n) {
    int idx = blockIdx.x * 256 + threadIdx.x;
    if (idx >= n) return;
    float s = 0.f;
#pragma unroll
    for (int u = 0; u < 10; ++u) s += part[(size_t)u*n + idx];
    inv[idx] = 1.0f / (1e-16f + sqrtf(s));
}

// ---------------- K4: split-bf16 MFMA GEMM, double-buffered counted-vmcnt pipeline ----------------
#define BM 128
#define BN 64
#define BK 32
#define NKT (CH/BK)        // 20
#define NCT 8
#define NRT 59
#define NWG (NCT*NRT*BATCH)   // 1888, divisible by 8
#define BUFB 24576
// buffer layout: AH[0,8K) AL[8K,16K) BH[16K,20K) BL[20K,24K); rows are 64B,
// 16B slot s of row holds global k-group (s ^ ((row>>2)&3))  -> 2-way reads (free)
__global__ __launch_bounds__(256) void k_gemm(
        const ushort* __restrict__ Ah, const ushort* __restrict__ Al,
        const ushort* __restrict__ Bh, const ushort* __restrict__ Bl,
        const float* __restrict__ invq, const float* __restrict__ invs,
        float* __restrict__ S) {
    __shared__ __align__(1024) char lds[49152];
    int hwid = blockIdx.x;
    int l = (hwid & 7) * (NWG/8) + (hwid >> 3);   // chunked XCD swizzle
    int ct = l & 7;
    int rt = (l >> 3) % NRT;
    int b  = l / (NCT*NRT);
    int t  = threadIdx.x;
    int lane = t & 63, w = t >> 6;
    int row0 = rt * BM, col0 = ct * BN;
    int t16w = w << 10;    // wave-uniform LDS chunk base

    // staging source offsets (pre-swizzled; LDS dest is linear wave chunks)
    size_t aoffA[2]; size_t boff0;
#pragma unroll
    for (int i = 0; i < 2; ++i) {
        int X = i*4096 + t*16;
        int row = X >> 6;
        int ks  = ((X >> 4) & 3) ^ ((row >> 2) & 3);
        int gr = row0 + row; if (gr > MTOT-1) gr = MTOT-1;
        aoffA[i] = ((size_t)b*MTOT + gr)*CH + ks*8;
    }
    {
        int X = t*16;
        int col = X >> 6;
        int ks  = ((X >> 4) & 3) ^ ((col >> 2) & 3);
        int gc = col0 + col; if (gc > MS-1) gc = MS-1;
        boff0 = ((size_t)b*MS + gc)*CH + ks*8;
    }

    f32x4 acc[4][2];
#pragma unroll
    for (int mi = 0; mi < 4; ++mi)
#pragma unroll
        for (int ni = 0; ni < 2; ++ni) acc[mi][ni] = (f32x4){0.f,0.f,0.f,0.f};

    int wr = w >> 1, wc = w & 1;
    int q = lane & 15, kg = lane >> 4;

#define STAGE(bufb, kt_) do { \
        size_t ka = (size_t)(kt_) * BK; \
        char* bb = lds + (bufb)*BUFB; \
        GLD_LDS16(Ah + aoffA[0] + ka, bb + 0     + t16w); \
        GLD_LDS16(Ah + aoffA[1] + ka, bb + 4096  + t16w); \
        GLD_LDS16(Al + aoffA[0] + ka, bb + 8192  + t16w); \
        GLD_LDS16(Al + aoffA[1] + ka, bb + 12288 + t16w); \
        GLD_LDS16(Bh + boff0    + ka, bb + 16384 + t16w); \
        GLD_LDS16(Bl + boff0    + ka, bb + 20480 + t16w); \
    } while (0)

    STAGE(0, 0);
    for (int kt = 0; kt < NKT; ++kt) {
        int cur = kt & 1;
        if (kt + 1 < NKT) {
            STAGE(cur ^ 1, kt + 1);
            asm volatile("s_waitcnt vmcnt(6)" ::: "memory");
        } else {
            asm volatile("s_waitcnt vmcnt(0)" ::: "memory");
        }
        __builtin_amdgcn_sched_barrier(0);
        __builtin_amdgcn_s_barrier();
        __builtin_amdgcn_sched_barrier(0);

        const char* base = lds + cur*BUFB;
        bf16x8 bh[2], bl[2];
#pragma unroll
        for (int ni = 0; ni < 2; ++ni) {
            int colr = wc*32 + ni*16 + q;
            int off = colr*64 + ((kg ^ ((colr >> 2) & 3)) << 4);
            bh[ni] = *(const bf16x8*)(base + 16384 + off);
            bl[ni] = *(const bf16x8*)(base + 20480 + off);
        }
#pragma unroll
        for (int mi = 0; mi < 4; ++mi) {
            int rowr = wr*64 + mi*16 + q;
            int off = rowr*64 + ((kg ^ ((rowr >> 2) & 3)) << 4);
            bf16x8 ah = *(const bf16x8*)(base + off);
            bf16x8 al = *(const bf16x8*)(base + 8192 + off);
#pragma unroll
            for (int ni = 0; ni < 2; ++ni) {
                acc[mi][ni] = __builtin_amdgcn_mfma_f32_16x16x32_bf16(ah, bh[ni], acc[mi][ni], 0, 0, 0);
                acc[mi][ni] = __builtin_amdgcn_mfma_f32_16x16x32_bf16(ah, bl[ni], acc[mi][ni], 0, 0, 0);
                acc[mi][ni] = __builtin_amdgcn_mfma_f32_16x16x32_bf16(al, bh[ni], acc[mi][ni], 0, 0, 0);
            }
        }
        __builtin_amdgcn_sched_barrier(0);
        __builtin_amdgcn_s_barrier();
        __builtin_amdgcn_sched_barrier(0);
    }
#undef STAGE

    int colb = col0 + wc*32 + q;
    int rowb = row0 + wr*64 + (kg << 2);
#pragma unroll
    for (int mi = 0; mi < 4; ++mi) {
#pragma unroll
        for (int ni = 0; ni < 2; ++ni) {
            int c = colb + ni*16;
            if (c >= MS) continue;
            float si = invs[b*MS + c];
#pragma unroll
            for (int j = 0; j < 4; ++j) {
                int r = rowb + mi*16 + j;
                if (r < MTOT)
                    S[((size_t)b*MTOT + r)*MS + c] = acc[mi][ni][j] * invq[b*MTOT + r] * si;
            }
        }
    }
}

// ---------------- K5: fused row(g20) + col(g10) softmax stats, single S pass ----------------
__global__ __launch_bounds__(512) void k_stats(const float* __restrict__ S,
        float* __restrict__ m20, float* __restrict__ rd20,
        float* __restrict__ m10, float* __restrict__ rd10) {
    __shared__ float wcm[8][512];
    __shared__ float wcs[8][512];
    int sys = blockIdx.x;
    int t = threadIdx.x;
    int w = t >> 6, l = t & 63;
    const float* Sb = S + (size_t)sys*MQ*MS;
    float colm[8], cols[8];
#pragma unroll
    for (int u = 0; u < 8; ++u) { colm[u] = -1e30f; cols[u] = 0.f; }
    int nu = (l < MS - 448) ? 8 : 7;   // l<52 -> 8 cols
    for (int row = w; row < MQ; row += 8) {
        const float* rp = Sb + (size_t)row*MS;
        float v[8];
        float rm = -1e30f;
#pragma unroll
        for (int u = 0; u < 8; ++u) {
            v[u] = (u < nu) ? rp[l + 64*u] : -1e30f;
            rm = fmaxf(rm, v[u]);
        }
        for (int off = 32; off; off >>= 1) rm = fmaxf(rm, __shfl_xor(rm, off));
        float rs = 0.f;
#pragma unroll
        for (int u = 0; u < 8; ++u) if (u < nu) rs += __expf(20.f*(v[u]-rm));
        for (int off = 32; off; off >>= 1) rs += __shfl_xor(rs, off);
        if (l == 0) { m20[sys*MQ+row] = rm; rd20[sys*MQ+row] = 1.0f/rs; }
#pragma unroll
        for (int u = 0; u < 8; ++u) if (u < nu) {
            float vv = v[u];
            if (vv <= colm[u]) {
                cols[u] += __expf(10.f*(vv - colm[u]));
            } else {
                cols[u] = cols[u]*__expf(10.f*(colm[u]-vv)) + 1.0f;
                colm[u] = vv;
            }
        }
    }
#pragma unroll
    for (int u = 0; u < 8; ++u) { wcm[w][l+64*u] = colm[u]; wcs[w][l+64*u] = cols[u]; }
    __syncthreads();
    if (t < MS) {
        float m = -1e30f;
#pragma unroll
        for (int w2 = 0; w2 < 8; ++w2) m = fmaxf(m, wcm[w2][t]);
        float s = 0.f;
#pragma unroll
        for (int w2 = 0; w2 < 8; ++w2) s += wcs[w2][t]*__expf(10.f*(wcm[w2][t]-m));
        m10[sys*MS+t] = m;
        rd10[sys*MS+t] = 1.0f/s;
    }
}

// ---------------- K6: partial B over a 100-col slice, reg accumulation ----------------
#define KC 50
#define NCH 2
#define NPART 5
#define PADP 102
__global__ __launch_bounds__(256) void k_formB_part(
        const float* __restrict__ S,
        const float* __restrict__ m10, const float* __restrict__ rd10,
        const float* __restrict__ m20, const float* __restrict__ rd20,
        float* __restrict__ Bpart, float* __restrict__ rspart) {
    __shared__ float PT[KC][PADP];   // PT[c][i] = P[i][col0+c]
    __shared__ float QT[KC][PADP];   // QT[c][j] = Q[j][col0+c]
    __shared__ float m20s[MQ], r20s[MQ];
    int part = blockIdx.x;
    int sys  = blockIdx.y;
    int t = threadIdx.x;
    int tx = t % 25, ty = t / 25;
    int j0 = tx*4, i0 = ty*10;
    float acc[10][4] = {};
    float rs = 0.f;
    const float* Sb   = S    + (size_t)sys*MQ*MS;
    const float* m10b = m10  + sys*MS;
    const float* r10b = rd10 + sys*MS;
    if (t < MQ) { m20s[t] = m20[sys*MQ+t]; r20s[t] = rd20[sys*MQ+t]; }

    for (int sub = 0; sub < NCH; ++sub) {
        int col0 = part*(KC*NCH) + sub*KC;
        __syncthreads();
        for (int ll = t; ll < MQ*KC; ll += 256) {
            int r = ll / KC, c = ll % KC;
            float v = Sb[(size_t)r*MS + col0 + c];
            PT[c][r] = __expf(10.f*(v - m10b[col0+c])) * r10b[col0+c];
            QT[c][r] = __expf(20.f*(v - m20s[r])) * r20s[r];
        }
        __syncthreads();
        if (t < MQ) {
#pragma unroll
            for (int c = 0; c < KC; ++c) rs += PT[c][t];
        }
        if (ty < 10) {
            for (int c = 0; c < KC; ++c) {
                float2 q01 = *(const float2*)&QT[c][j0];
                float2 q23 = *(const float2*)&QT[c][j0+2];
                float2 p[5];
#pragma unroll
                for (int u = 0; u < 5; ++u) p[u] = *(const float2*)&PT[c][i0+2*u];
#pragma unroll
                for (int u = 0; u < 5; ++u) {
                    acc[2*u  ][0] += p[u].x*q01.x; acc[2*u  ][1] += p[u].x*q01.y;
                    acc[2*u  ][2] += p[u].x*q23.x; acc[2*u  ][3] += p[u].x*q23.y;
                    acc[2*u+1][0] += p[u].y*q01.x; acc[2*u+1][1] += p[u].y*q01.y;
                    acc[2*u+1][2] += p[u].y*q23.x; acc[2*u+1][3] += p[u].y*q23.y;
                }
            }
        }
    }
    if (ty < 10) {
        float* Bp = Bpart + ((size_t)part*NSYS + sys)*(MQ*MQ);
#pragma unroll
        for (int ii = 0; ii < 10; ++ii) {
            float4 v = make_float4(acc[ii][0], acc[ii][1], acc[ii][2], acc[ii][3]);
            *(float4*)&Bp[(i0+ii)*MQ + j0] = v;
        }
    }
    if (t < MQ) rspart[((size_t)part*NSYS + sys)*MQ + t] = rs;
}

// ---------------- K7: sum partials, Jacobi solve (I - 0.25 B) x = rhs, normalize ----------------
__global__ __launch_bounds__(256) void k_solve(
        const float* __restrict__ Bpart, const float* __restrict__ rspart,
        float* __restrict__ out) {
    __shared__ float Bsh[MQ][MQ+1];
    __shared__ float xs[MQ];
    __shared__ float rh[MQ];
    __shared__ float partial[4];
    int sys = blockIdx.x;
    int t = threadIdx.x;
    for (int ll = t; ll < MQ*MQ; ll += 256) {
        float s = 0.f;
#pragma unroll
        for (int p = 0; p < NPART; ++p)
            s += Bpart[((size_t)p*NSYS + sys)*(MQ*MQ) + ll];
        Bsh[ll/MQ][ll%MQ] = s;
    }
    if (t < MQ) {
        float rsum = 0.f;
#pragma unroll
        for (int p = 0; p < NPART; ++p)
            rsum += rspart[((size_t)p*NSYS + sys)*MQ + t];
        rh[t] = 1.0f + 0.5f*rsum;
        xs[t] = rh[t];
    }
    __syncthreads();
    for (int it = 0; it < 30; ++it) {
        float s = 0.f;
        if (t < MQ) {
            for (int j = 0; j < MQ; ++j) s += Bsh[t][j]*xs[j];
        }
        __syncthreads();
        if (t < MQ) xs[t] = rh[t] + 0.25f*s;
        __syncthreads();
    }
    float kv = (t < MQ) ? (xs[t] - 1.0f) : 0.f;
    float s = kv;
    for (int off = 32; off; off >>= 1) s += __shfl_xor(s, off);
    if ((t & 63) == 0) partial[t >> 6] = s;
    __syncthreads();
    float tot = partial[0] + partial[1] + partial[2] + partial[3];
    if (t < MQ) out[sys*MQ + t] = kv / tot;
}

extern "C" void kernel_launch(void* const* d_in, const int* in_sizes, int n_in,
                              void* d_out, int out_size, void* d_ws, size_t ws_size,
                              hipStream_t stream) {
    const float* sup = (const float*)d_in[0];
    const float* qry = (const float*)d_in[1];
    float* out = (float*)d_out;
    float* ws  = (float*)d_ws;

    float* supmean = ws;                        // 1,280,000 f
    float* invs    = supmean + 1280000;         // 2,000
    float* invq    = invs + 2000;               // 30,000
    float* Smat    = invq + 30000;              // 15,000,000
    float* m20     = Smat + 15000000;           // 30,000
    float* rd20    = m20 + 30000;               // 30,000
    float* m10     = rd20 + 30000;              // 150,000
    float* rd10    = m10 + 150000;              // 150,000
    float* Bm      = rd10 + 150000;             // 3,000,000 (norm partials live here)
    float* rh      = Bm + 3000000;              // 30,000 (unused)
    ushort* Ahh    = (ushort*)(rh + 30000);     // 19,200,000 u16
    ushort* All    = Ahh + 19200000;            // 19,200,000
    ushort* Bhh    = All + 19200000;            // 1,280,000
    ushort* Bll    = Bhh + 1280000;             // 1,280,000
    float* npq     = Bm;                        // 10 x 30000
    float* nps     = Bm + 300000;               // 10 x 2000
    float* Bpart   = (float*)Ahh;               // 15,000,000 f (aliases dead A-split)
    float* rspart  = Bpart + 15000000;          // 150,000 f

    k_supmean<<<(BATCH*NWAY*CH*HW + 255)/256, 256, 0, stream>>>(sup, supmean);
    k_prep<<<dim3(10, 2, BATCH*NQ),   256, 0, stream>>>(qry,     Ahh, All, npq, NSYS*HW);
    k_prep<<<dim3(10, 2, BATCH*NWAY), 256, 0, stream>>>(supmean, Bhh, Bll, nps, BATCH*NWAY*HW);
    k_finishinv<<<(NSYS*HW + 255)/256, 256, 0, stream>>>(npq, invq, NSYS*HW);
    k_finishinv<<<(BATCH*NWAY*HW + 255)/256, 256, 0, stream>>>(nps, invs, BATCH*NWAY*HW);
    k_gemm<<<NWG, 256, 0, stream>>>(Ahh, All, Bhh, Bll, invq, invs, Smat);
    k_stats<<<NSYS, 512, 0, stream>>>(Smat, m20, rd20, m10, rd10);
    k_formB_part<<<dim3(NPART, NSYS), 256, 0, stream>>>(Smat, m10, rd10, m20, rd20, Bpart, rspart);
    k_solve<<<NSYS, 256, 0, stream>>>(Bpart, rspart, out);
}

// Round 6
// 266.595 us; speedup vs baseline: 2.2151x; 1.0502x over previous
//
#include <hip/hip_runtime.h>
#include <math.h>

#define BATCH 4
#define NSUP 25
#define NQ   75
#define CH   640
#define HW   100
#define NWAY 5
#define KSHOT 5
#define NSYS (BATCH*NQ)   // 300
#define MS   (NWAY*HW)    // 500
#define MQ   HW           // 100
#define MTOT (NQ*HW)      // 7500 rows per batch

typedef __attribute__((ext_vector_type(8))) short bf16x8;
typedef __attribute__((ext_vector_type(4))) float f32x4;

__device__ __forceinline__ ushort f2bf(float f) {
    unsigned u = __float_as_uint(f);
    u += 0x7fff + ((u >> 16) & 1);          // RNE
    return (ushort)(u >> 16);
}
__device__ __forceinline__ float bf2f(ushort h) {
    return __uint_as_float(((unsigned)h) << 16);
}

#define GLD_LDS16(gp, lp) __builtin_amdgcn_global_load_lds( \
    (const __attribute__((address_space(1))) unsigned*)(const void*)(gp), \
    (__attribute__((address_space(3))) unsigned*)(void*)(lp), 16, 0, 0)

// ---------------- K1: transpose + raw bf16 hi/lo split + norm partials (query) ----------------
__global__ __launch_bounds__(256) void k_prep(const float* __restrict__ in,
        ushort* __restrict__ hi, ushort* __restrict__ lo,
        float* __restrict__ normpart, int planesHW) {
    __shared__ float tile[64][65];
    int p  = blockIdx.z;
    int c0 = blockIdx.x * 64;
    int m0 = blockIdx.y * 64;
    int t  = threadIdx.x;
    const float* ib = in + (size_t)p*CH*HW;
#pragma unroll
    for (int i = 0; i < 16; ++i) {
        int l = i*256 + t;
        int cl = l >> 6, ml = l & 63;
        int m = m0 + ml;
        tile[cl][ml] = (m < HW) ? ib[(size_t)(c0+cl)*HW + m] : 0.f;
    }
    __syncthreads();
    if (t < 64 && (m0 + t) < HW) {
        float s = 0.f;
#pragma unroll
        for (int cl = 0; cl < 64; ++cl) { float v = tile[cl][t]; s += v*v; }
        normpart[(size_t)blockIdx.x*planesHW + p*HW + m0 + t] = s;
    }
#pragma unroll
    for (int i = 0; i < 16; ++i) {
        int l = i*256 + t;
        int ml = l >> 6, cl = l & 63;
        int m = m0 + ml;
        if (m < HW) {
            size_t r = (size_t)p*HW + m;
            float v = tile[cl][ml];
            ushort h = f2bf(v);
            float fl = v - bf2f(h);
            hi[r*CH + c0 + cl] = h;
            lo[r*CH + c0 + cl] = f2bf(fl);
        }
    }
}

// ---------------- K1b: support variant — fused 5-shot class mean ----------------
__global__ __launch_bounds__(256) void k_prep_sup(const float* __restrict__ sup,
        ushort* __restrict__ hi, ushort* __restrict__ lo,
        float* __restrict__ normpart) {
    __shared__ float tile[64][65];
    int p  = blockIdx.z;              // b*NWAY + n
    int c0 = blockIdx.x * 64;
    int m0 = blockIdx.y * 64;
    int t  = threadIdx.x;
    int b = p / NWAY, n = p % NWAY;
    const float* ib = sup + ((size_t)(b*NSUP + n*KSHOT))*CH*HW;
#pragma unroll
    for (int i = 0; i < 16; ++i) {
        int l = i*256 + t;
        int cl = l >> 6, ml = l & 63;
        int m = m0 + ml;
        float a = 0.f;
        if (m < HW) {
#pragma unroll
            for (int k = 0; k < KSHOT; ++k)
                a += ib[((size_t)k*CH + c0 + cl)*HW + m];
        }
        tile[cl][ml] = a * 0.2f;
    }
    __syncthreads();
    if (t < 64 && (m0 + t) < HW) {
        float s = 0.f;
#pragma unroll
        for (int cl = 0; cl < 64; ++cl) { float v = tile[cl][t]; s += v*v; }
        normpart[(size_t)blockIdx.x*(BATCH*NWAY*HW) + p*HW + m0 + t] = s;
    }
#pragma unroll
    for (int i = 0; i < 16; ++i) {
        int l = i*256 + t;
        int ml = l >> 6, cl = l & 63;
        int m = m0 + ml;
        if (m < HW) {
            size_t r = (size_t)p*HW + m;
            float v = tile[cl][ml];
            ushort h = f2bf(v);
            float fl = v - bf2f(h);
            hi[r*CH + c0 + cl] = h;
            lo[r*CH + c0 + cl] = f2bf(fl);
        }
    }
}

// ---------------- K2: finish inverse norms (query + support merged) ----------------
__global__ void k_finishinv(const float* __restrict__ pq, const float* __restrict__ ps,
                            float* __restrict__ invq, float* __restrict__ invs) {
    int idx = blockIdx.x * 256 + threadIdx.x;
    if (idx < NSYS*HW) {
        float s = 0.f;
#pragma unroll
        for (int u = 0; u < 10; ++u) s += pq[(size_t)u*(NSYS*HW) + idx];
        invq[idx] = 1.0f / (1e-16f + sqrtf(s));
    } else {
        int j = idx - NSYS*HW;
        if (j < BATCH*NWAY*HW) {
            float s = 0.f;
#pragma unroll
            for (int u = 0; u < 10; ++u) s += ps[(size_t)u*(BATCH*NWAY*HW) + j];
            invs[j] = 1.0f / (1e-16f + sqrtf(s));
        }
    }
}

// ---------------- K3: split-bf16 MFMA GEMM, dbuf + counted vmcnt, 128B-row swizzle ----------------
#define BM 128
#define BN 64
#define BK 32
#define NKT (CH/BK)           // 20
#define NCT 8
#define NRT 59
#define NWG (NCT*NRT*BATCH)   // 1888, divisible by 8
#define BUFB 24576
// Per buffer: A rows 0..127 at r*128, B rows 0..63 at 16384 + r*128.
// Row = 8 slots of 16B; logical slot s (s<4: hi k-group s, s>=4: lo k-group s-4)
// stored at slot sp = s ^ (r&7).  128B row stride => 8-slot XOR covers all 32
// banks over 8 rows; residual 2-way is free (m136). Measured 0-conflict in R3/R4.
__global__ __launch_bounds__(256) void k_gemm(
        const ushort* __restrict__ Ah, const ushort* __restrict__ Al,
        const ushort* __restrict__ Bh, const ushort* __restrict__ Bl,
        const float* __restrict__ invq, const float* __restrict__ invs,
        float* __restrict__ S) {
    __shared__ __align__(1024) char lds[49152];
    int hwid = blockIdx.x;
    int l = (hwid & 7) * (NWG/8) + (hwid >> 3);   // chunked XCD swizzle
    int ct = l & 7;
    int rt = (l >> 3) % NRT;
    int b  = l / (NCT*NRT);
    int t  = threadIdx.x;
    int lane = t & 63, w = t >> 6;
    int row0 = rt * BM, col0 = ct * BN;

    // per-thread staging sources: chunk i lives at LDS byte i*4096 + t*16
    const ushort* srcA[4];
    const ushort* srcB[2];
#pragma unroll
    for (int i = 0; i < 4; ++i) {
        int X = i*4096 + t*16;
        int row = X >> 7;
        int sp  = (X >> 4) & 7;
        int s   = sp ^ (row & 7);
        int gr = row0 + row; if (gr > MTOT-1) gr = MTOT-1;
        srcA[i] = ((s & 4) ? Al : Ah) + ((size_t)b*MTOT + gr)*CH + (s & 3)*8;
    }
#pragma unroll
    for (int i = 0; i < 2; ++i) {
        int X = i*4096 + t*16;
        int row = X >> 7;
        int sp  = (X >> 4) & 7;
        int s   = sp ^ (row & 7);
        int gc = col0 + row; if (gc > MS-1) gc = MS-1;
        srcB[i] = ((s & 4) ? Bl : Bh) + ((size_t)b*MS + gc)*CH + (s & 3)*8;
    }
    int dA = w << 10;   // wave-uniform dest base within each 4KB chunk region

    f32x4 acc[4][2];
#pragma unroll
    for (int mi = 0; mi < 4; ++mi)
#pragma unroll
        for (int ni = 0; ni < 2; ++ni) acc[mi][ni] = (f32x4){0.f,0.f,0.f,0.f};

    int wr = w >> 1, wc = w & 1;
    int q = lane & 15, kg = lane >> 4;

#define STAGE(bufb, kt_) do { \
        int ko = (kt_) * BK; \
        char* bb = lds + (bufb)*BUFB; \
        GLD_LDS16(srcA[0] + ko, bb + 0     + dA); \
        GLD_LDS16(srcA[1] + ko, bb + 4096  + dA); \
        GLD_LDS16(srcA[2] + ko, bb + 8192  + dA); \
        GLD_LDS16(srcA[3] + ko, bb + 12288 + dA); \
        GLD_LDS16(srcB[0] + ko, bb + 16384 + dA); \
        GLD_LDS16(srcB[1] + ko, bb + 20480 + dA); \
    } while (0)

    STAGE(0, 0);
    for (int kt = 0; kt < NKT; ++kt) {
        int cur = kt & 1;
        if (kt + 1 < NKT) {
            STAGE(cur ^ 1, kt + 1);
            asm volatile("s_waitcnt vmcnt(6)" ::: "memory");
        } else {
            asm volatile("s_waitcnt vmcnt(0)" ::: "memory");
        }
        __builtin_amdgcn_sched_barrier(0);
        __builtin_amdgcn_s_barrier();
        __builtin_amdgcn_sched_barrier(0);

        const char* base = lds + cur*BUFB;
        bf16x8 bh[2], bl[2];
#pragma unroll
        for (int ni = 0; ni < 2; ++ni) {
            int colr = wc*32 + ni*16 + q;
            int rb = 16384 + colr*128;
            bh[ni] = *(const bf16x8*)(base + rb + (((kg    ) ^ (colr & 7)) << 4));
            bl[ni] = *(const bf16x8*)(base + rb + (((kg | 4) ^ (colr & 7)) << 4));
        }
#pragma unroll
        for (int mi = 0; mi < 4; ++mi) {
            int rowr = wr*64 + mi*16 + q;
            int rb = rowr*128;
            bf16x8 ah = *(const bf16x8*)(base + rb + (((kg    ) ^ (rowr & 7)) << 4));
            bf16x8 al = *(const bf16x8*)(base + rb + (((kg | 4) ^ (rowr & 7)) << 4));
#pragma unroll
            for (int ni = 0; ni < 2; ++ni) {
                acc[mi][ni] = __builtin_amdgcn_mfma_f32_16x16x32_bf16(ah, bh[ni], acc[mi][ni], 0, 0, 0);
                acc[mi][ni] = __builtin_amdgcn_mfma_f32_16x16x32_bf16(ah, bl[ni], acc[mi][ni], 0, 0, 0);
                acc[mi][ni] = __builtin_amdgcn_mfma_f32_16x16x32_bf16(al, bh[ni], acc[mi][ni], 0, 0, 0);
            }
        }
        __builtin_amdgcn_sched_barrier(0);
        __builtin_amdgcn_s_barrier();
        __builtin_amdgcn_sched_barrier(0);
    }
#undef STAGE

    int colb = col0 + wc*32 + q;
    int rowb = row0 + wr*64 + (kg << 2);
#pragma unroll
    for (int mi = 0; mi < 4; ++mi) {
#pragma unroll
        for (int ni = 0; ni < 2; ++ni) {
            int c = colb + ni*16;
            if (c >= MS) continue;
            float si = invs[b*MS + c];
#pragma unroll
            for (int j = 0; j < 4; ++j) {
                int r = rowb + mi*16 + j;
                if (r < MTOT)
                    S[((size_t)b*MTOT + r)*MS + c] = acc[mi][ni][j] * invq[b*MTOT + r] * si;
            }
        }
    }
}

// ---------------- K4: fused row(g20) + col(g10) softmax stats, single S pass ----------------
__global__ __launch_bounds__(512) void k_stats(const float* __restrict__ S,
        float* __restrict__ m20, float* __restrict__ rd20,
        float* __restrict__ m10, float* __restrict__ rd10) {
    __shared__ float wcm[8][512];
    __shared__ float wcs[8][512];
    int sys = blockIdx.x;
    int t = threadIdx.x;
    int w = t >> 6, l = t & 63;
    const float* Sb = S + (size_t)sys*MQ*MS;
    float colm[8], cols[8];
#pragma unroll
    for (int u = 0; u < 8; ++u) { colm[u] = -1e30f; cols[u] = 0.f; }
    int nu = (l < MS - 448) ? 8 : 7;   // l<52 -> 8 cols
    for (int row = w; row < MQ; row += 8) {
        const float* rp = Sb + (size_t)row*MS;
        float v[8];
        float rm = -1e30f;
#pragma unroll
        for (int u = 0; u < 8; ++u) {
            v[u] = (u < nu) ? rp[l + 64*u] : -1e30f;
            rm = fmaxf(rm, v[u]);
        }
        for (int off = 32; off; off >>= 1) rm = fmaxf(rm, __shfl_xor(rm, off));
        float rs = 0.f;
#pragma unroll
        for (int u = 0; u < 8; ++u) if (u < nu) rs += __expf(20.f*(v[u]-rm));
        for (int off = 32; off; off >>= 1) rs += __shfl_xor(rs, off);
        if (l == 0) { m20[sys*MQ+row] = rm; rd20[sys*MQ+row] = 1.0f/rs; }
#pragma unroll
        for (int u = 0; u < 8; ++u) if (u < nu) {
            float vv = v[u];
            if (vv <= colm[u]) {
                cols[u] += __expf(10.f*(vv - colm[u]));
            } else {
                cols[u] = cols[u]*__expf(10.f*(colm[u]-vv)) + 1.0f;
                colm[u] = vv;
            }
        }
    }
#pragma unroll
    for (int u = 0; u < 8; ++u) { wcm[w][l+64*u] = colm[u]; wcs[w][l+64*u] = cols[u]; }
    __syncthreads();
    if (t < MS) {
        float m = -1e30f;
#pragma unroll
        for (int w2 = 0; w2 < 8; ++w2) m = fmaxf(m, wcm[w2][t]);
        float s = 0.f;
#pragma unroll
        for (int w2 = 0; w2 < 8; ++w2) s += wcs[w2][t]*__expf(10.f*(wcm[w2][t]-m));
        m10[sys*MS+t] = m;
        rd10[sys*MS+t] = 1.0f/s;
    }
}

// ---------------- K5: partial B over a 100-col slice, reg accumulation ----------------
#define KC 50
#define NCH 2
#define NPART 5
#define PADP 102
__global__ __launch_bounds__(256) void k_formB_part(
        const float* __restrict__ S,
        const float* __restrict__ m10, const float* __restrict__ rd10,
        const float* __restrict__ m20, const float* __restrict__ rd20,
        float* __restrict__ Bpart, float* __restrict__ rspart) {
    __shared__ float PT[KC][PADP];   // PT[c][i] = P[i][col0+c]
    __shared__ float QT[KC][PADP];   // QT[c][j] = Q[j][col0+c]
    __shared__ float m20s[MQ], r20s[MQ];
    int part = blockIdx.x;
    int sys  = blockIdx.y;
    int t = threadIdx.x;
    int tx = t % 25, ty = t / 25;
    int j0 = tx*4, i0 = ty*10;
    float acc[10][4] = {};
    float rs = 0.f;
    const float* Sb   = S    + (size_t)sys*MQ*MS;
    const float* m10b = m10  + sys*MS;
    const float* r10b = rd10 + sys*MS;
    if (t < MQ) { m20s[t] = m20[sys*MQ+t]; r20s[t] = rd20[sys*MQ+t]; }

    for (int sub = 0; sub < NCH; ++sub) {
        int col0 = part*(KC*NCH) + sub*KC;
        __syncthreads();
        for (int ll = t; ll < MQ*KC; ll += 256) {
            int r = ll / KC, c = ll % KC;
            float v = Sb[(size_t)r*MS + col0 + c];
            PT[c][r] = __expf(10.f*(v - m10b[col0+c])) * r10b[col0+c];
            QT[c][r] = __expf(20.f*(v - m20s[r])) * r20s[r];
        }
        __syncthreads();
        if (t < MQ) {
#pragma unroll
            for (int c = 0; c < KC; ++c) rs += PT[c][t];
        }
        if (ty < 10) {
            for (int c = 0; c < KC; ++c) {
                float2 q01 = *(const float2*)&QT[c][j0];
                float2 q23 = *(const float2*)&QT[c][j0+2];
                float2 p[5];
#pragma unroll
                for (int u = 0; u < 5; ++u) p[u] = *(const float2*)&PT[c][i0+2*u];
#pragma unroll
                for (int u = 0; u < 5; ++u) {
                    acc[2*u  ][0] += p[u].x*q01.x; acc[2*u  ][1] += p[u].x*q01.y;
                    acc[2*u  ][2] += p[u].x*q23.x; acc[2*u  ][3] += p[u].x*q23.y;
                    acc[2*u+1][0] += p[u].y*q01.x; acc[2*u+1][1] += p[u].y*q01.y;
                    acc[2*u+1][2] += p[u].y*q23.x; acc[2*u+1][3] += p[u].y*q23.y;
                }
            }
        }
    }
    if (ty < 10) {
        float* Bp = Bpart + ((size_t)part*NSYS + sys)*(MQ*MQ);
#pragma unroll
        for (int ii = 0; ii < 10; ++ii) {
            float4 v = make_float4(acc[ii][0], acc[ii][1], acc[ii][2], acc[ii][3]);
            *(float4*)&Bp[(i0+ii)*MQ + j0] = v;
        }
    }
    if (t < MQ) rspart[((size_t)part*NSYS + sys)*MQ + t] = rs;
}

// ---------------- K6: sum partials, Jacobi solve (I - 0.25 B) x = rhs, normalize ----------------
__global__ __launch_bounds__(256) void k_solve(
        const float* __restrict__ Bpart, const float* __restrict__ rspart,
        float* __restrict__ out) {
    __shared__ float Bsh[MQ][MQ+1];
    __shared__ float xs[MQ];
    __shared__ float rh[MQ];
    __shared__ float partial[4];
    int sys = blockIdx.x;
    int t = threadIdx.x;
    for (int ll = t; ll < MQ*MQ; ll += 256) {
        float s = 0.f;
#pragma unroll
        for (int p = 0; p < NPART; ++p)
            s += Bpart[((size_t)p*NSYS + sys)*(MQ*MQ) + ll];
        Bsh[ll/MQ][ll%MQ] = s;
    }
    if (t < MQ) {
        float rsum = 0.f;
#pragma unroll
        for (int p = 0; p < NPART; ++p)
            rsum += rspart[((size_t)p*NSYS + sys)*MQ + t];
        rh[t] = 1.0f + 0.5f*rsum;
        xs[t] = rh[t];
    }
    __syncthreads();
    for (int it = 0; it < 30; ++it) {
        float s = 0.f;
        if (t < MQ) {
            for (int j = 0; j < MQ; ++j) s += Bsh[t][j]*xs[j];
        }
        __syncthreads();
        if (t < MQ) xs[t] = rh[t] + 0.25f*s;
        __syncthreads();
    }
    float kv = (t < MQ) ? (xs[t] - 1.0f) : 0.f;
    float s = kv;
    for (int off = 32; off; off >>= 1) s += __shfl_xor(s, off);
    if ((t & 63) == 0) partial[t >> 6] = s;
    __syncthreads();
    float tot = partial[0] + partial[1] + partial[2] + partial[3];
    if (t < MQ) out[sys*MQ + t] = kv / tot;
}

extern "C" void kernel_launch(void* const* d_in, const int* in_sizes, int n_in,
                              void* d_out, int out_size, void* d_ws, size_t ws_size,
                              hipStream_t stream) {
    const float* sup = (const float*)d_in[0];
    const float* qry = (const float*)d_in[1];
    float* out = (float*)d_out;
    float* ws  = (float*)d_ws;

    float* supmean = ws;                        // 1,280,000 f (unused, layout keeper)
    float* invs    = supmean + 1280000;         // 2,000
    float* invq    = invs + 2000;               // 30,000
    float* Smat    = invq + 30000;              // 15,000,000
    float* m20     = Smat + 15000000;           // 30,000
    float* rd20    = m20 + 30000;               // 30,000
    float* m10     = rd20 + 30000;              // 150,000
    float* rd10    = m10 + 150000;              // 150,000
    float* Bm      = rd10 + 150000;             // 3,000,000 (norm partials)
    float* rh      = Bm + 3000000;              // 30,000 (unused)
    ushort* Ahh    = (ushort*)(rh + 30000);     // 19,200,000 u16
    ushort* All    = Ahh + 19200000;            // 19,200,000
    ushort* Bhh    = All + 19200000;            // 1,280,000
    ushort* Bll    = Bhh + 1280000;             // 1,280,000
    float* npq     = Bm;                        // 10 x 30000
    float* nps     = Bm + 300000;               // 10 x 2000
    float* Bpart   = (float*)Ahh;               // 15,000,000 f (aliases dead A-split)
    float* rspart  = Bpart + 15000000;          // 150,000 f

    k_prep<<<dim3(10, 2, BATCH*NQ), 256, 0, stream>>>(qry, Ahh, All, npq, NSYS*HW);
    k_prep_sup<<<dim3(10, 2, BATCH*NWAY), 256, 0, stream>>>(sup, Bhh, Bll, nps);
    k_finishinv<<<(NSYS*HW + BATCH*NWAY*HW + 255)/256, 256, 0, stream>>>(npq, nps, invq, invs);
    k_gemm<<<NWG, 256, 0, stream>>>(Ahh, All, Bhh, Bll, invq, invs, Smat);
    k_stats<<<NSYS, 512, 0, stream>>>(Smat, m20, rd20, m10, rd10);
    k_formB_part<<<dim3(NPART, NSYS), 256, 0, stream>>>(Smat, m10, rd10, m20, rd20, Bpart, rspart);
    k_solve<<<NSYS, 256, 0, stream>>>(Bpart, rspart, out);
}